// Round 1
// baseline (3680.039 us; speedup 1.0000x reference)
//
#include <hip/hip_runtime.h>
#include <math.h>

// ---------------------------------------------------------------------------
// CapsNet forward, fp32.  Pipeline:
//  conv1 (1->256, k9 s1, relu) -> conv2/PrimaryCaps (256->256, k9 s2) ->
//  squash(8) -> dynamic routing (3 iters, u_hat recomputed on the fly) ->
//  class softmax over batch + argmax mask -> 3-layer decoder MLP.
// ---------------------------------------------------------------------------

// ======================= conv1: [256,1,28,28] -> [256,256,20,20] ============
// grid 1024 = 256 b x 4 co-groups(64 co); block 320 = 16 co-quads x 20 oy
__global__ __launch_bounds__(320) void conv1_kernel(
    const float* __restrict__ data, const float* __restrict__ w1,
    const float* __restrict__ b1, float* __restrict__ x1)
{
  const int bid = blockIdx.x;
  const int b   = bid >> 2;
  const int cog = bid & 3;
  __shared__ float img[784];
  __shared__ float wsm[81][64];
  const int t = threadIdx.x;
  for (int i = t; i < 784; i += 320) img[i] = data[b * 784 + i];
  for (int i = t; i < 64 * 81; i += 320) {
    int col = i / 81, k = i % 81;
    wsm[k][col] = w1[(cog * 64 + col) * 81 + k];
  }
  __syncthreads();
  const int cg = t & 15;
  const int oy = t >> 4;           // 0..19
  const int co0 = cog * 64 + cg * 4;
  float acc[4][20];
  #pragma unroll
  for (int i = 0; i < 4; i++) {
    float bv = b1[co0 + i];
    #pragma unroll
    for (int j = 0; j < 20; j++) acc[i][j] = bv;
  }
  for (int ky = 0; ky < 9; ky++) {
    float xr[28];
    const float4* rp = reinterpret_cast<const float4*>(&img[(oy + ky) * 28]);
    #pragma unroll
    for (int q = 0; q < 7; q++) {
      float4 v4 = rp[q];
      xr[q*4+0] = v4.x; xr[q*4+1] = v4.y; xr[q*4+2] = v4.z; xr[q*4+3] = v4.w;
    }
    #pragma unroll
    for (int kx = 0; kx < 9; kx++) {
      float4 wv = *reinterpret_cast<const float4*>(&wsm[ky * 9 + kx][cg * 4]);
      #pragma unroll
      for (int ox = 0; ox < 20; ox++) {
        float xv = xr[ox + kx];
        acc[0][ox] = fmaf(xv, wv.x, acc[0][ox]);
        acc[1][ox] = fmaf(xv, wv.y, acc[1][ox]);
        acc[2][ox] = fmaf(xv, wv.z, acc[2][ox]);
        acc[3][ox] = fmaf(xv, wv.w, acc[3][ox]);
      }
    }
  }
  #pragma unroll
  for (int i = 0; i < 4; i++)
    for (int ox = 0; ox < 20; ox++) {
      float v = acc[i][ox];
      x1[((b * 256 + co0 + i) * 20 + oy) * 20 + ox] = v > 0.f ? v : 0.f;
    }
}

// ============ transpose conv2 weights [co][ci][81] -> [ci][81][co] ==========
// grid 1024 = 256 ci x 4 co-tiles(64); block 256
__global__ void transpose_w2(const float* __restrict__ pw, float* __restrict__ wt)
{
  const int ci  = blockIdx.x & 255;
  const int cot = blockIdx.x >> 8;
  __shared__ float wsm[81][64];
  const int t = threadIdx.x;
  for (int i = t; i < 64 * 81; i += 256) {
    int col = i / 81, k = i % 81;
    wsm[k][col] = pw[((cot * 64 + col) * 256 + ci) * 81 + k];
  }
  __syncthreads();
  for (int i = t; i < 81 * 64; i += 256) {
    int k = i >> 6, col = i & 63;
    wt[ci * 20736 + k * 256 + cot * 64 + col] = wsm[k][col];
  }
}

// ===== conv2: [256,256,20,20] -> partial [2][256][256][6][6], k9 s2 =========
// grid 512: bp(128) x cot(2) x kh(2, split-K over ci); block 384 = 2b x 6oy x 32cg
__global__ __launch_bounds__(384) void conv2_kernel(
    const float* __restrict__ x1, const float* __restrict__ wt,
    float* __restrict__ part)
{
  const int bid = blockIdx.x;
  const int bp  = bid & 127;
  const int cot = (bid >> 7) & 1;
  const int kh  = bid >> 8;
  __shared__ float xs[2][400];
  __shared__ float wsm[81][128];
  const int t  = threadIdx.x;
  const int cg = t & 31;
  const int oy = (t >> 5) % 6;
  const int bl = t / 192;
  const int b  = bp * 2 + bl;
  float acc[4][6];
  #pragma unroll
  for (int i = 0; i < 4; i++)
    for (int j = 0; j < 6; j++) acc[i][j] = 0.f;
  const int ci0 = kh * 128;
  for (int cc = 0; cc < 128; cc++) {
    const int ci = ci0 + cc;
    __syncthreads();
    for (int i = t; i < 800; i += 384) {
      int bb = i / 400, off = i % 400;
      xs[bb][off] = x1[((bp * 2 + bb) * 256 + ci) * 400 + off];
    }
    for (int i = t; i < 81 * 128; i += 384) {
      int k = i >> 7, col = i & 127;
      wsm[k][col] = wt[ci * 20736 + k * 256 + cot * 128 + col];
    }
    __syncthreads();
    for (int ky = 0; ky < 9; ky++) {
      float xr[20];
      const float4* rp = reinterpret_cast<const float4*>(&xs[bl][(2 * oy + ky) * 20]);
      #pragma unroll
      for (int q = 0; q < 5; q++) {
        float4 v4 = rp[q];
        xr[q*4+0] = v4.x; xr[q*4+1] = v4.y; xr[q*4+2] = v4.z; xr[q*4+3] = v4.w;
      }
      #pragma unroll
      for (int kx = 0; kx < 9; kx++) {
        float4 wv = *reinterpret_cast<const float4*>(&wsm[ky * 9 + kx][cg * 4]);
        #pragma unroll
        for (int ox = 0; ox < 6; ox++) {
          float xv = xr[2 * ox + kx];
          acc[0][ox] = fmaf(xv, wv.x, acc[0][ox]);
          acc[1][ox] = fmaf(xv, wv.y, acc[1][ox]);
          acc[2][ox] = fmaf(xv, wv.z, acc[2][ox]);
          acc[3][ox] = fmaf(xv, wv.w, acc[3][ox]);
        }
      }
    }
  }
  const int co0 = cot * 128 + cg * 4;
  #pragma unroll
  for (int i = 0; i < 4; i++)
    for (int ox = 0; ox < 6; ox++)
      part[(kh * 256 + b) * 9216 + (co0 + i) * 36 + oy * 6 + ox] = acc[i][ox];
}

// ======== combine split-K partials + bias, then squash groups of 8 ==========
// grid 1152 x 256: one thread per route (b,r)
__global__ void combine_squash(const float* __restrict__ part,
                               const float* __restrict__ pb, float* __restrict__ u)
{
  const int id = blockIdx.x * 256 + threadIdx.x;  // 0..294911
  const int b = id / 1152;
  const int r = id % 1152;
  const float* p0 = part + b * 9216 + r * 8;
  const float* p1 = part + (256 + b) * 9216 + r * 8;
  float4 a0 = *(const float4*)p0, a1 = *(const float4*)(p0 + 4);
  float4 c0 = *(const float4*)p1, c1 = *(const float4*)(p1 + 4);
  float v[8];
  v[0]=a0.x+c0.x; v[1]=a0.y+c0.y; v[2]=a0.z+c0.z; v[3]=a0.w+c0.w;
  v[4]=a1.x+c1.x; v[5]=a1.y+c1.y; v[6]=a1.z+c1.z; v[7]=a1.w+c1.w;
  #pragma unroll
  for (int i = 0; i < 8; i++) v[i] += pb[(r * 8 + i) / 36];
  float sq = 0.f;
  #pragma unroll
  for (int i = 0; i < 8; i++) sq += v[i] * v[i];
  float scale = sq / ((1.f + sq) * sqrtf(sq));
  #pragma unroll
  for (int i = 0; i < 8; i++) u[b * 9216 + r * 8 + i] = v[i] * scale;
}

// ================== softmax over routes (per class column) ==================
__global__ void route_softmax(const float* __restrict__ bij, float* __restrict__ cij)
{
  const int c = blockIdx.x;
  const int t = threadIdx.x;
  __shared__ float red[8];
  float m = -1e30f;
  for (int r = t; r < 1152; r += 256) m = fmaxf(m, bij[c * 1152 + r]);
  for (int off = 32; off; off >>= 1) m = fmaxf(m, __shfl_down(m, off, 64));
  if ((t & 63) == 0) red[t >> 6] = m;
  __syncthreads();
  m = fmaxf(fmaxf(red[0], red[1]), fmaxf(red[2], red[3]));
  float s = 0.f;
  for (int r = t; r < 1152; r += 256) {
    float e = expf(bij[c * 1152 + r] - m);
    cij[c * 1152 + r] = e;
    s += e;
  }
  for (int off = 32; off; off >>= 1) s += __shfl_down(s, off, 64);
  if ((t & 63) == 0) red[4 + (t >> 6)] = s;
  __syncthreads();
  float inv = 1.f / (red[4] + red[5] + red[6] + red[7]);
  for (int r = t; r < 1152; r += 256) cij[c * 1152 + r] *= inv;
}

// ===== s_j[b,c,o] = sum_r c[r,c] * dot(W[r,c,o,:], u[b,r,:])  ===============
// grid 640 = 10 c x 64 b-quads; block 256 (thread strides routes)
__global__ __launch_bounds__(256) void s_pass(
    const float* __restrict__ u, const float* __restrict__ W,
    const float* __restrict__ cij, float* __restrict__ s, int uniform)
{
  const int c  = blockIdx.x % 10;
  const int b0 = (blockIdx.x / 10) * 4;
  const int t  = threadIdx.x;
  float acc[4][16];
  #pragma unroll
  for (int bb = 0; bb < 4; bb++)
    for (int o = 0; o < 16; o++) acc[bb][o] = 0.f;
  for (int r = t; r < 1152; r += 256) {
    float cw = uniform ? (1.f / 1152.f) : cij[c * 1152 + r];
    float u8[4][8];
    #pragma unroll
    for (int bb = 0; bb < 4; bb++) {
      const float4* up = (const float4*)(u + (b0 + bb) * 9216 + r * 8);
      float4 x0 = up[0], x1 = up[1];
      u8[bb][0]=x0.x*cw; u8[bb][1]=x0.y*cw; u8[bb][2]=x0.z*cw; u8[bb][3]=x0.w*cw;
      u8[bb][4]=x1.x*cw; u8[bb][5]=x1.y*cw; u8[bb][6]=x1.z*cw; u8[bb][7]=x1.w*cw;
    }
    const float4* Wp = (const float4*)(W + (r * 10 + c) * 128);
    #pragma unroll
    for (int o = 0; o < 16; o++) {
      float4 wa = Wp[o * 2], wb = Wp[o * 2 + 1];
      #pragma unroll
      for (int bb = 0; bb < 4; bb++) {
        float d = wa.x*u8[bb][0] + wa.y*u8[bb][1] + wa.z*u8[bb][2] + wa.w*u8[bb][3]
                + wb.x*u8[bb][4] + wb.y*u8[bb][5] + wb.z*u8[bb][6] + wb.w*u8[bb][7];
        acc[bb][o] += d;
      }
    }
  }
  __shared__ float lred[4][64];
  const int lane = t & 63, wid = t >> 6;
  #pragma unroll
  for (int bb = 0; bb < 4; bb++)
    #pragma unroll
    for (int o = 0; o < 16; o++) {
      float val = acc[bb][o];
      for (int off = 32; off; off >>= 1) val += __shfl_down(val, off, 64);
      if (lane == 0) lred[wid][bb * 16 + o] = val;
    }
  __syncthreads();
  if (t < 64) {
    float v = lred[0][t] + lred[1][t] + lred[2][t] + lred[3][t];
    int bb = t >> 4, o = t & 15;
    s[(b0 + bb) * 160 + c * 16 + o] = v;
  }
}

// ======================== v = squash(s) over 16 dims ========================
// grid 10 x 256: thread id = b*10+c
__global__ void squash_v(const float* __restrict__ s, float* __restrict__ v,
                         float* __restrict__ outp, float* __restrict__ norms, int final_it)
{
  const int id = blockIdx.x * 256 + threadIdx.x;  // b*10+c
  const float4* sp = (const float4*)(s + id * 16);
  float x[16];
  #pragma unroll
  for (int q = 0; q < 4; q++) {
    float4 v4 = sp[q];
    x[q*4+0]=v4.x; x[q*4+1]=v4.y; x[q*4+2]=v4.z; x[q*4+3]=v4.w;
  }
  float sq = 0.f;
  #pragma unroll
  for (int k = 0; k < 16; k++) sq += x[k] * x[k];
  float nrm = sqrtf(sq);
  float scale = sq / ((1.f + sq) * nrm);
  #pragma unroll
  for (int k = 0; k < 16; k++) {
    float vv = x[k] * scale;
    v[id * 16 + k] = vv;
    if (final_it) outp[id * 16 + k] = vv;
  }
  if (final_it) norms[id] = scale * nrm;
}

// == a[r,c] = (1/B) sum_{b,o} dot(W[r,c,o],u[b,r]) * v[b,c,o]; bij (+)= a ====
// grid 1152 (r); block 256 (thread = b)
__global__ __launch_bounds__(256) void a_pass(
    const float* __restrict__ u, const float* __restrict__ W,
    const float* __restrict__ v, float* __restrict__ bij, int assign)
{
  const int r = blockIdx.x;
  const int t = threadIdx.x;
  __shared__ float wsl[1280];
  __shared__ float lred[4][10];
  for (int i = t; i < 1280; i += 256) wsl[i] = W[r * 1280 + i];
  __syncthreads();
  float u8[8];
  {
    const float4* up = (const float4*)(u + t * 9216 + r * 8);
    float4 x0 = up[0], x1 = up[1];
    u8[0]=x0.x; u8[1]=x0.y; u8[2]=x0.z; u8[3]=x0.w;
    u8[4]=x1.x; u8[5]=x1.y; u8[6]=x1.z; u8[7]=x1.w;
  }
  float partial[10];
  #pragma unroll
  for (int c = 0; c < 10; c++) {
    const float* wc = &wsl[c * 128];
    const float4* vp = (const float4*)(v + t * 160 + c * 16);
    float4 v0 = vp[0], v1 = vp[1], v2 = vp[2], v3 = vp[3];
    float vv[16] = {v0.x,v0.y,v0.z,v0.w, v1.x,v1.y,v1.z,v1.w,
                    v2.x,v2.y,v2.z,v2.w, v3.x,v3.y,v3.z,v3.w};
    float p = 0.f;
    #pragma unroll
    for (int o = 0; o < 16; o++) {
      float d = wc[o*8+0]*u8[0] + wc[o*8+1]*u8[1] + wc[o*8+2]*u8[2] + wc[o*8+3]*u8[3]
              + wc[o*8+4]*u8[4] + wc[o*8+5]*u8[5] + wc[o*8+6]*u8[6] + wc[o*8+7]*u8[7];
      p += d * vv[o];
    }
    partial[c] = p;
  }
  const int lane = t & 63, wid = t >> 6;
  #pragma unroll
  for (int c = 0; c < 10; c++) {
    float val = partial[c];
    for (int off = 32; off; off >>= 1) val += __shfl_down(val, off, 64);
    if (lane == 0) lred[wid][c] = val;
  }
  __syncthreads();
  if (t < 10) {
    float a = (lred[0][t] + lred[1][t] + lred[2][t] + lred[3][t]) * (1.f / 256.f);
    float o = assign ? 0.f : bij[t * 1152 + r];
    bij[t * 1152 + r] = o + a;
  }
}

// ================= softmax of class norms over the batch axis ===============
// grid 10 (c); block 256 (thread = b)
__global__ void batch_softmax(const float* __restrict__ norms, float* __restrict__ scores)
{
  const int c = blockIdx.x;
  const int t = threadIdx.x;
  __shared__ float red[8];
  float x = norms[t * 10 + c];
  float m = x;
  for (int off = 32; off; off >>= 1) m = fmaxf(m, __shfl_down(m, off, 64));
  if ((t & 63) == 0) red[t >> 6] = m;
  __syncthreads();
  m = fmaxf(fmaxf(red[0], red[1]), fmaxf(red[2], red[3]));
  float e = expf(x - m);
  float ssum = e;
  for (int off = 32; off; off >>= 1) ssum += __shfl_down(ssum, off, 64);
  if ((t & 63) == 0) red[4 + (t >> 6)] = ssum;
  __syncthreads();
  scores[t * 10 + c] = e / (red[4] + red[5] + red[6] + red[7]);
}

// ============ argmax over classes, one-hot mask, masked t vector ============
__global__ void mask_t_kernel(const float* __restrict__ scores, const float* __restrict__ v,
                              float* __restrict__ masked, float* __restrict__ tbuf)
{
  const int b = threadIdx.x;
  float best = scores[b * 10];
  int idx = 0;
  for (int c = 1; c < 10; c++) {
    float sc = scores[b * 10 + c];
    if (sc > best) { best = sc; idx = c; }
  }
  for (int c = 0; c < 10; c++) {
    float msk = (c == idx) ? 1.f : 0.f;
    masked[b * 10 + c] = msk;
    for (int o = 0; o < 16; o++)
      tbuf[b * 160 + c * 16 + o] = v[b * 160 + c * 16 + o] * msk;
  }
}

// ==================== small GEMM: C = act(A[M,K] @ B[K,N] + bias) ===========
// 64x64 tile, BK=16, 256 threads, 4x4 per thread.  ACT 0=relu, 1=sigmoid
template <int ACT>
__global__ __launch_bounds__(256) void gemm_act(
    const float* __restrict__ A, const float* __restrict__ B,
    const float* __restrict__ bias, float* __restrict__ C, int M, int N, int K)
{
  __shared__ float As[64][17];
  __shared__ float Bs[16][64];
  const int t = threadIdx.x;
  const int tx = t & 15, ty = t >> 4;
  const int m0 = blockIdx.y * 64, n0 = blockIdx.x * 64;
  float acc[4][4] = {};
  for (int kb = 0; kb < K; kb += 16) {
    {
      int row = t >> 2, c4 = (t & 3) * 4;
      float4 av = *(const float4*)(A + (m0 + row) * K + kb + c4);
      As[row][c4+0]=av.x; As[row][c4+1]=av.y; As[row][c4+2]=av.z; As[row][c4+3]=av.w;
    }
    {
      int row = t >> 4, c4 = (t & 15) * 4;
      float4 bv = make_float4(0.f, 0.f, 0.f, 0.f);
      if (n0 + c4 < N) bv = *(const float4*)(B + (kb + row) * N + n0 + c4);
      Bs[row][c4+0]=bv.x; Bs[row][c4+1]=bv.y; Bs[row][c4+2]=bv.z; Bs[row][c4+3]=bv.w;
    }
    __syncthreads();
    #pragma unroll
    for (int kk = 0; kk < 16; kk++) {
      float a_[4], b_[4];
      #pragma unroll
      for (int i = 0; i < 4; i++) a_[i] = As[ty * 4 + i][kk];
      #pragma unroll
      for (int j = 0; j < 4; j++) b_[j] = Bs[kk][tx * 4 + j];
      #pragma unroll
      for (int i = 0; i < 4; i++)
        for (int j = 0; j < 4; j++)
          acc[i][j] = fmaf(a_[i], b_[j], acc[i][j]);
    }
    __syncthreads();
  }
  #pragma unroll
  for (int i = 0; i < 4; i++) {
    int row = m0 + ty * 4 + i;
    #pragma unroll
    for (int j = 0; j < 4; j++) {
      int col = n0 + tx * 4 + j;
      if (col < N) {
        float val = acc[i][j] + bias[col];
        if (ACT == 0) val = val > 0.f ? val : 0.f;
        else          val = 1.f / (1.f + expf(-val));
        C[row * N + col] = val;
      }
    }
  }
}

// ===========================================================================
extern "C" void kernel_launch(void* const* d_in, const int* in_sizes, int n_in,
                              void* d_out, int out_size, void* d_ws, size_t ws_size,
                              hipStream_t stream)
{
  const float* data = (const float*)d_in[0];
  const float* w1   = (const float*)d_in[1];
  const float* b1   = (const float*)d_in[2];
  const float* pw   = (const float*)d_in[3];
  const float* pb   = (const float*)d_in[4];
  const float* Wdc  = (const float*)d_in[5];
  const float* dw1  = (const float*)d_in[6];
  const float* db1  = (const float*)d_in[7];
  const float* dw2  = (const float*)d_in[8];
  const float* db2  = (const float*)d_in[9];
  const float* dw3  = (const float*)d_in[10];
  const float* db3  = (const float*)d_in[11];

  float* out     = (float*)d_out;
  float* outp    = out;              // [256][10][16][1]
  float* recon   = out + 40960;      // [256][784]
  float* maskedo = out + 241664;     // [256][10]

  float* ws    = (float*)d_ws;
  float* x1    = ws;                  // 26,214,400
  float* wt    = x1 + 26214400;       //  5,308,416
  float* part  = wt + 5308416;        //  4,718,592 (2 x split-K partials)
  float* u     = part + 4718592;      //  2,359,296
  float* bij   = u + 2359296;         //     11,520
  float* cij   = bij + 11520;         //     11,520
  float* sbuf  = cij + 11520;         //     40,960
  float* vbuf  = sbuf + 40960;        //     40,960
  float* norms = vbuf + 40960;        //      2,560
  float* score = norms + 2560;        //      2,560
  float* tbuf  = score + 2560;        //     40,960
  float* h1    = tbuf + 40960;        //    131,072
  float* h2    = h1 + 131072;         //    262,144

  conv1_kernel<<<1024, 320, 0, stream>>>(data, w1, b1, x1);
  transpose_w2<<<1024, 256, 0, stream>>>(pw, wt);
  conv2_kernel<<<512, 384, 0, stream>>>(x1, wt, part);
  combine_squash<<<1152, 256, 0, stream>>>(part, pb, u);

  // routing iteration 0 (b_ij = 0  ->  c uniform); b_ij assigned, not added
  s_pass<<<640, 256, 0, stream>>>(u, Wdc, cij, sbuf, 1);
  squash_v<<<10, 256, 0, stream>>>(sbuf, vbuf, outp, norms, 0);
  a_pass<<<1152, 256, 0, stream>>>(u, Wdc, vbuf, bij, 1);
  // iteration 1
  route_softmax<<<10, 256, 0, stream>>>(bij, cij);
  s_pass<<<640, 256, 0, stream>>>(u, Wdc, cij, sbuf, 0);
  squash_v<<<10, 256, 0, stream>>>(sbuf, vbuf, outp, norms, 0);
  a_pass<<<1152, 256, 0, stream>>>(u, Wdc, vbuf, bij, 0);
  // iteration 2 (final: also writes d_out `output` region and class norms)
  route_softmax<<<10, 256, 0, stream>>>(bij, cij);
  s_pass<<<640, 256, 0, stream>>>(u, Wdc, cij, sbuf, 0);
  squash_v<<<10, 256, 0, stream>>>(sbuf, vbuf, outp, norms, 1);

  // decoder
  batch_softmax<<<10, 256, 0, stream>>>(norms, score);
  mask_t_kernel<<<1, 256, 0, stream>>>(score, vbuf, maskedo, tbuf);
  gemm_act<0><<<dim3(8, 4),  256, 0, stream>>>(tbuf, dw1, db1, h1,    256, 512,  160);
  gemm_act<0><<<dim3(16, 4), 256, 0, stream>>>(h1,   dw2, db2, h2,    256, 1024, 512);
  gemm_act<1><<<dim3(13, 4), 256, 0, stream>>>(h2,   dw3, db3, recon, 256, 784,  1024);
}

// Round 2
// 1821.083 us; speedup vs baseline: 2.0208x; 2.0208x over previous
//
#include <hip/hip_runtime.h>
#include <math.h>

// ---------------------------------------------------------------------------
// CapsNet forward.  conv1 fp32 -> split to bf16(hi,lo) channel-last ->
// conv2 as implicit-GEMM MFMA (bf16x2 compensated, fp32 accum) ->
// squash -> routing (coalesced layouts) -> decoder MLP (fp32).
// ---------------------------------------------------------------------------

typedef __attribute__((ext_vector_type(8))) short short8;
typedef __attribute__((ext_vector_type(4))) float f32x4;

__device__ __forceinline__ unsigned short f2bf(float x) {
  unsigned int u = __float_as_uint(x);
  unsigned int r = (u + 0x7fffu + ((u >> 16) & 1u)) >> 16;
  return (unsigned short)r;
}
__device__ __forceinline__ float bf2f(unsigned short h) {
  return __uint_as_float(((unsigned int)h) << 16);
}
__device__ __forceinline__ void gload16(const void* g, void* l) {
  __builtin_amdgcn_global_load_lds(
      (const __attribute__((address_space(1))) unsigned int*)g,
      (__attribute__((address_space(3))) unsigned int*)l, 16, 0, 0);
}
__device__ __forceinline__ float dot8(const float* w, float4 a, float4 b) {
  return w[0]*a.x + w[1]*a.y + w[2]*a.z + w[3]*a.w +
         w[4]*b.x + w[5]*b.y + w[6]*b.z + w[7]*b.w;
}

// ======================= conv1: [256,1,28,28] -> bf16x2 CL [256,20,20,256] ==
// grid 1024 = 256 b x 4 co-groups(64 co); block 320 = 16 co-quads x 20 oy
__global__ __launch_bounds__(320) void conv1_kernel(
    const float* __restrict__ data, const float* __restrict__ w1,
    const float* __restrict__ b1, unsigned short* __restrict__ xh,
    unsigned short* __restrict__ xl)
{
  const int bid = blockIdx.x;
  const int b   = bid >> 2;
  const int cog = bid & 3;
  __shared__ float img[784];
  __shared__ float wsm[81][64];
  const int t = threadIdx.x;
  for (int i = t; i < 784; i += 320) img[i] = data[b * 784 + i];
  for (int i = t; i < 64 * 81; i += 320) {
    int col = i / 81, k = i % 81;
    wsm[k][col] = w1[(cog * 64 + col) * 81 + k];
  }
  __syncthreads();
  const int cg = t & 15;
  const int oy = t >> 4;           // 0..19
  const int co0 = cog * 64 + cg * 4;
  float acc[4][20];
  #pragma unroll
  for (int i = 0; i < 4; i++) {
    float bv = b1[co0 + i];
    #pragma unroll
    for (int j = 0; j < 20; j++) acc[i][j] = bv;
  }
  for (int ky = 0; ky < 9; ky++) {
    float xr[28];
    const float4* rp = reinterpret_cast<const float4*>(&img[(oy + ky) * 28]);
    #pragma unroll
    for (int q = 0; q < 7; q++) {
      float4 v4 = rp[q];
      xr[q*4+0] = v4.x; xr[q*4+1] = v4.y; xr[q*4+2] = v4.z; xr[q*4+3] = v4.w;
    }
    #pragma unroll
    for (int kx = 0; kx < 9; kx++) {
      float4 wv = *reinterpret_cast<const float4*>(&wsm[ky * 9 + kx][cg * 4]);
      #pragma unroll
      for (int ox = 0; ox < 20; ox++) {
        float xv = xr[ox + kx];
        acc[0][ox] = fmaf(xv, wv.x, acc[0][ox]);
        acc[1][ox] = fmaf(xv, wv.y, acc[1][ox]);
        acc[2][ox] = fmaf(xv, wv.z, acc[2][ox]);
        acc[3][ox] = fmaf(xv, wv.w, acc[3][ox]);
      }
    }
  }
  #pragma unroll
  for (int ox = 0; ox < 20; ox++) {
    ushort4 hv, lv;
    float v0 = fmaxf(acc[0][ox], 0.f), v1 = fmaxf(acc[1][ox], 0.f);
    float v2 = fmaxf(acc[2][ox], 0.f), v3 = fmaxf(acc[3][ox], 0.f);
    hv.x = f2bf(v0); lv.x = f2bf(v0 - bf2f(hv.x));
    hv.y = f2bf(v1); lv.y = f2bf(v1 - bf2f(hv.y));
    hv.z = f2bf(v2); lv.z = f2bf(v2 - bf2f(hv.z));
    hv.w = f2bf(v3); lv.w = f2bf(v3 - bf2f(hv.w));
    const int pix = (b * 20 + oy) * 20 + ox;
    *(ushort4*)(xh + pix * 256 + co0) = hv;
    *(ushort4*)(xl + pix * 256 + co0) = lv;
  }
}

// ===== conv2 weight prep: pw[co][ci][81] fp32 -> w[k][co][ci] bf16 hi/lo ====
// grid 256 (co); block 256 (ci)
__global__ void wprep(const float* __restrict__ pw, unsigned short* __restrict__ wh,
                      unsigned short* __restrict__ wl)
{
  const int co = blockIdx.x, ci = threadIdx.x;
  const float* src = pw + (co * 256 + ci) * 81;
  for (int k = 0; k < 81; k++) {
    float x = src[k];
    unsigned short h = f2bf(x);
    wh[(k * 256 + co) * 256 + ci] = h;
    wl[(k * 256 + co) * 256 + ci] = f2bf(x - bf2f(h));
  }
}

// ===== routing weight prep: Wdc[r][c][o][8] -> Wrt[c][o][r][8] ==============
__global__ void wprep2(const float* __restrict__ Wdc, float* __restrict__ Wrt)
{
  const int id = blockIdx.x * 256 + threadIdx.x;   // < 1,474,560
  const int i = id & 7;
  const int o = (id >> 3) & 15;
  const int rc = id >> 7;
  const int c = rc % 10, r = rc / 10;
  Wrt[((c * 16 + o) * 1152 + r) * 8 + i] = Wdc[id];
}

// ===== conv2 MFMA: M=64 pix x N=256 co, K=32-ci chunks, 3-way ky split ======
// grid 432 = 144 m-tiles x 3 ky-groups; block 256 (4 waves); 80KB dynamic LDS
__global__ __launch_bounds__(256) void conv2_mfma(
    const unsigned short* __restrict__ xh, const unsigned short* __restrict__ xl,
    const unsigned short* __restrict__ wh, const unsigned short* __restrict__ wl,
    float* __restrict__ part)
{
  extern __shared__ char lds[];
  const int t   = threadIdx.x;
  const int blk = blockIdx.x;
  const int mt  = blk % 144;
  const int kg  = blk / 144;
  const int m0  = mt * 64;
  const int lane = t & 63;
  const int w    = t >> 6;
  const int l15  = lane & 15, l4 = lane >> 4;
  const int n0   = w * 64;

  // A staging address precompute: thread t -> (pix row = t>>2, ci-oct = t&3)
  const int arow = t >> 2, aoct = t & 3;
  const int apix = m0 + arow;
  const int ab  = apix / 36;
  const int asp = apix - ab * 36;
  const int aoy = asp / 6;
  const int aox = asp - aoy * 6;
  const int abase = ((ab * 20 + 2 * aoy) * 20 + 2 * aox) * 256 + aoct * 8;
  // B staging: iter i covers co = i*64 + (t>>2), oct = t&3
  const int bofs0 = (t >> 2) * 256 + (t & 3) * 8;

  f32x4 acc[4][4];
  #pragma unroll
  for (int i = 0; i < 4; i++)
    #pragma unroll
    for (int j = 0; j < 4; j++) acc[i][j] = (f32x4){0.f, 0.f, 0.f, 0.f};

  const int ky0 = kg * 3;

  auto stage = [&](int buf, int ky, int kx, int ci0) {
    char* base = lds + buf * 40960;
    const int axy = (ky * 20 + kx) * 256;
    const int wxy = (ky * 9 + kx) * 65536;
    gload16(xh + abase + axy + ci0, base + t * 16);
    gload16(xl + abase + axy + ci0, base + 4096 + t * 16);
    const unsigned short* wph = wh + wxy + ci0 + bofs0;
    const unsigned short* wpl = wl + wxy + ci0 + bofs0;
    char* bhd = base + 8192  + t * 16;
    char* bld = base + 24576 + t * 16;
    #pragma unroll
    for (int i = 0; i < 4; i++) {
      gload16(wph + i * 16384, bhd + i * 4096);
      gload16(wpl + i * 16384, bld + i * 4096);
    }
  };

  stage(0, ky0, 0, 0);
  __syncthreads();

  int kyn = ky0, kxn = 0, ccn = 0;
  #pragma unroll 1
  for (int s = 0; s < 216; ++s) {
    const int cur = s & 1;
    ccn++;
    if (ccn == 8) { ccn = 0; kxn++; if (kxn == 9) { kxn = 0; kyn++; } }
    if (s < 215) stage(cur ^ 1, kyn, kxn, ccn * 32);

    char* base = lds + cur * 40960;
    short8 a_h[4], a_l[4], b_h[4], b_l[4];
    #pragma unroll
    for (int mf = 0; mf < 4; mf++) {
      const int off = ((mf * 16 + l15) << 6) + (l4 << 4);
      a_h[mf] = *(const short8*)(base + off);
      a_l[mf] = *(const short8*)(base + 4096 + off);
    }
    #pragma unroll
    for (int nf = 0; nf < 4; nf++) {
      const int off = ((nf * 16 + l15) << 6) + (l4 << 4);
      b_h[nf] = *(const short8*)(base + 8192  + (n0 << 6) + off);
      b_l[nf] = *(const short8*)(base + 24576 + (n0 << 6) + off);
    }
    #pragma unroll
    for (int mf = 0; mf < 4; mf++)
      #pragma unroll
      for (int nf = 0; nf < 4; nf++) {
        acc[mf][nf] = __builtin_amdgcn_mfma_f32_16x16x32_bf16(a_h[mf], b_h[nf], acc[mf][nf], 0, 0, 0);
        acc[mf][nf] = __builtin_amdgcn_mfma_f32_16x16x32_bf16(a_l[mf], b_h[nf], acc[mf][nf], 0, 0, 0);
        acc[mf][nf] = __builtin_amdgcn_mfma_f32_16x16x32_bf16(a_h[mf], b_l[nf], acc[mf][nf], 0, 0, 0);
      }
    __syncthreads();
  }

  // epilogue: C[row=pix][col=co]; lane holds col=l15, rows l4*4+reg
  float* pout = part + kg * 2359296;
  #pragma unroll
  for (int mf = 0; mf < 4; mf++) {
    #pragma unroll
    for (int reg = 0; reg < 4; reg++) {
      const int pix = m0 + mf * 16 + l4 * 4 + reg;
      const int b  = pix / 36;
      const int sp = pix - b * 36;
      float* pb_ = pout + b * 9216 + sp;
      #pragma unroll
      for (int nf = 0; nf < 4; nf++) {
        const int co = n0 + nf * 16 + l15;
        pb_[co * 36] = acc[mf][nf][reg];
      }
    }
  }
}

// ======== combine 3 split-K partials + bias, squash(8); emit u and u_T ======
__global__ void combine_squash(const float* __restrict__ part,
                               const float* __restrict__ pb,
                               float* __restrict__ u, float* __restrict__ uT)
{
  const int id = blockIdx.x * 256 + threadIdx.x;  // 0..294911
  const int b = id / 1152;
  const int r = id % 1152;
  const float* p0 = part + b * 9216 + r * 8;
  float v[8];
  #pragma unroll
  for (int i = 0; i < 8; i++) v[i] = p0[i] + p0[2359296 + i] + p0[4718592 + i];
  #pragma unroll
  for (int i = 0; i < 8; i++) v[i] += pb[(r * 8 + i) / 36];
  float sq = 0.f;
  #pragma unroll
  for (int i = 0; i < 8; i++) sq += v[i] * v[i];
  float scale = sq / ((1.f + sq) * sqrtf(sq));
  #pragma unroll
  for (int i = 0; i < 8; i++) {
    float o = v[i] * scale;
    u[b * 9216 + r * 8 + i] = o;
    uT[(r * 256 + b) * 8 + i] = o;
  }
}

// ================== softmax over routes (per class column) ==================
__global__ void route_softmax(const float* __restrict__ bij, float* __restrict__ cij)
{
  const int c = blockIdx.x;
  const int t = threadIdx.x;
  __shared__ float red[8];
  float m = -1e30f;
  for (int r = t; r < 1152; r += 256) m = fmaxf(m, bij[c * 1152 + r]);
  for (int off = 32; off; off >>= 1) m = fmaxf(m, __shfl_down(m, off, 64));
  if ((t & 63) == 0) red[t >> 6] = m;
  __syncthreads();
  m = fmaxf(fmaxf(red[0], red[1]), fmaxf(red[2], red[3]));
  float s = 0.f;
  for (int r = t; r < 1152; r += 256) {
    float e = expf(bij[c * 1152 + r] - m);
    cij[c * 1152 + r] = e;
    s += e;
  }
  for (int off = 32; off; off >>= 1) s += __shfl_down(s, off, 64);
  if ((t & 63) == 0) red[4 + (t >> 6)] = s;
  __syncthreads();
  float inv = 1.f / (red[4] + red[5] + red[6] + red[7]);
  for (int r = t; r < 1152; r += 256) cij[c * 1152 + r] *= inv;
}

// ===== s_j[b,c,o] = sum_r c[r,c] * dot(W[r,c,o,:], u[b,r,:])  (Wrt layout) ==
__global__ __launch_bounds__(256) void s_pass(
    const float* __restrict__ u, const float* __restrict__ Wrt,
    const float* __restrict__ cij, float* __restrict__ s, int uniform)
{
  const int c  = blockIdx.x % 10;
  const int b0 = (blockIdx.x / 10) * 4;
  const int t  = threadIdx.x;
  float acc[4][16];
  #pragma unroll
  for (int bb = 0; bb < 4; bb++)
    #pragma unroll
    for (int o = 0; o < 16; o++) acc[bb][o] = 0.f;
  for (int r = t; r < 1152; r += 256) {
    float cw = uniform ? (1.f / 1152.f) : cij[c * 1152 + r];
    float4 ua[4], ub[4];
    #pragma unroll
    for (int bb = 0; bb < 4; bb++) {
      const float4* up = (const float4*)(u + (b0 + bb) * 9216 + r * 8);
      float4 x0 = up[0], x1 = up[1];
      ua[bb] = make_float4(x0.x*cw, x0.y*cw, x0.z*cw, x0.w*cw);
      ub[bb] = make_float4(x1.x*cw, x1.y*cw, x1.z*cw, x1.w*cw);
    }
    const float* wbase = Wrt + c * 147456 + r * 8;
    #pragma unroll
    for (int o = 0; o < 16; o++) {
      float4 wa = *(const float4*)(wbase + o * 9216);
      float4 wb = *(const float4*)(wbase + o * 9216 + 4);
      #pragma unroll
      for (int bb = 0; bb < 4; bb++)
        acc[bb][o] += wa.x*ua[bb].x + wa.y*ua[bb].y + wa.z*ua[bb].z + wa.w*ua[bb].w
                    + wb.x*ub[bb].x + wb.y*ub[bb].y + wb.z*ub[bb].z + wb.w*ub[bb].w;
    }
  }
  __shared__ float lred[4][64];
  const int lane = t & 63, wid = t >> 6;
  #pragma unroll
  for (int bb = 0; bb < 4; bb++)
    #pragma unroll
    for (int o = 0; o < 16; o++) {
      float val = acc[bb][o];
      for (int off = 32; off; off >>= 1) val += __shfl_down(val, off, 64);
      if (lane == 0) lred[wid][bb * 16 + o] = val;
    }
  __syncthreads();
  if (t < 64) {
    float v = lred[0][t] + lred[1][t] + lred[2][t] + lred[3][t];
    int bb = t >> 4, o = t & 15;
    s[(b0 + bb) * 160 + c * 16 + o] = v;
  }
}

// ======================== v = squash(s); emit v, v_T, outp, norms ===========
__global__ void squash_v(const float* __restrict__ s, float* __restrict__ v,
                         float* __restrict__ vT, float* __restrict__ outp,
                         float* __restrict__ norms, int final_it)
{
  const int id = blockIdx.x * 256 + threadIdx.x;  // b*10+c
  const int b = id / 10, c = id - b * 10;
  const float4* sp = (const float4*)(s + id * 16);
  float x[16];
  #pragma unroll
  for (int q = 0; q < 4; q++) {
    float4 v4 = sp[q];
    x[q*4+0]=v4.x; x[q*4+1]=v4.y; x[q*4+2]=v4.z; x[q*4+3]=v4.w;
  }
  float sq = 0.f;
  #pragma unroll
  for (int k = 0; k < 16; k++) sq += x[k] * x[k];
  float nrm = sqrtf(sq);
  float scale = sq / ((1.f + sq) * nrm);
  #pragma unroll
  for (int k = 0; k < 16; k++) {
    float vv = x[k] * scale;
    v[id * 16 + k] = vv;
    vT[(c * 256 + b) * 16 + k] = vv;
    if (final_it) outp[id * 16 + k] = vv;
  }
  if (final_it) norms[id] = scale * nrm;
}

// == a[r,c] = (1/B) sum_{b,o} dot(W[r,c,o],u[b,r]) * v[b,c,o]; bij (+)= a ====
__global__ __launch_bounds__(256) void a_pass(
    const float* __restrict__ uT, const float* __restrict__ W,
    const float* __restrict__ vT, float* __restrict__ bij, int assign)
{
  const int r = blockIdx.x;
  const int t = threadIdx.x;
  __shared__ float wsl[1280];
  __shared__ float lred[4][10];
  for (int i = t; i < 1280; i += 256) wsl[i] = W[r * 1280 + i];
  __syncthreads();
  const float4* up = (const float4*)(uT + (r * 256 + t) * 8);
  float4 ua = up[0], ub = up[1];
  float partial[10];
  #pragma unroll
  for (int c = 0; c < 10; c++) {
    const float* wc = &wsl[c * 128];
    const float4* vp = (const float4*)(vT + (c * 256 + t) * 16);
    float p = 0.f;
    #pragma unroll
    for (int q = 0; q < 4; q++) {
      float4 vq = vp[q];
      float vv[4] = {vq.x, vq.y, vq.z, vq.w};
      #pragma unroll
      for (int j = 0; j < 4; j++)
        p += dot8(wc + (q * 4 + j) * 8, ua, ub) * vv[j];
    }
    partial[c] = p;
  }
  const int lane = t & 63, wid = t >> 6;
  #pragma unroll
  for (int c = 0; c < 10; c++) {
    float val = partial[c];
    for (int off = 32; off; off >>= 1) val += __shfl_down(val, off, 64);
    if (lane == 0) lred[wid][c] = val;
  }
  __syncthreads();
  if (t < 10) {
    float a = (lred[0][t] + lred[1][t] + lred[2][t] + lred[3][t]) * (1.f / 256.f);
    float o = assign ? 0.f : bij[t * 1152 + r];
    bij[t * 1152 + r] = o + a;
  }
}

// ================= softmax of class norms over the batch axis ===============
__global__ void batch_softmax(const float* __restrict__ norms, float* __restrict__ scores)
{
  const int c = blockIdx.x;
  const int t = threadIdx.x;
  __shared__ float red[8];
  float x = norms[t * 10 + c];
  float m = x;
  for (int off = 32; off; off >>= 1) m = fmaxf(m, __shfl_down(m, off, 64));
  if ((t & 63) == 0) red[t >> 6] = m;
  __syncthreads();
  m = fmaxf(fmaxf(red[0], red[1]), fmaxf(red[2], red[3]));
  float e = expf(x - m);
  float ssum = e;
  for (int off = 32; off; off >>= 1) ssum += __shfl_down(ssum, off, 64);
  if ((t & 63) == 0) red[4 + (t >> 6)] = ssum;
  __syncthreads();
  scores[t * 10 + c] = e / (red[4] + red[5] + red[6] + red[7]);
}

// ============ argmax over classes, one-hot mask, masked t vector ============
__global__ void mask_t_kernel(const float* __restrict__ scores, const float* __restrict__ v,
                              float* __restrict__ masked, float* __restrict__ tbuf)
{
  const int b = threadIdx.x;
  float best = scores[b * 10];
  int idx = 0;
  for (int c = 1; c < 10; c++) {
    float sc = scores[b * 10 + c];
    if (sc > best) { best = sc; idx = c; }
  }
  for (int c = 0; c < 10; c++) {
    float msk = (c == idx) ? 1.f : 0.f;
    masked[b * 10 + c] = msk;
    for (int o = 0; o < 16; o++)
      tbuf[b * 160 + c * 16 + o] = v[b * 160 + c * 16 + o] * msk;
  }
}

// ==================== small GEMM: C = act(A[M,K] @ B[K,N] + bias) ===========
template <int ACT>
__global__ __launch_bounds__(256) void gemm_act(
    const float* __restrict__ A, const float* __restrict__ B,
    const float* __restrict__ bias, float* __restrict__ C, int M, int N, int K)
{
  __shared__ float As[64][17];
  __shared__ float Bs[16][64];
  const int t = threadIdx.x;
  const int tx = t & 15, ty = t >> 4;
  const int m0 = blockIdx.y * 64, n0 = blockIdx.x * 64;
  float acc[4][4] = {};
  for (int kb = 0; kb < K; kb += 16) {
    {
      int row = t >> 2, c4 = (t & 3) * 4;
      float4 av = *(const float4*)(A + (m0 + row) * K + kb + c4);
      As[row][c4+0]=av.x; As[row][c4+1]=av.y; As[row][c4+2]=av.z; As[row][c4+3]=av.w;
    }
    {
      int row = t >> 4, c4 = (t & 15) * 4;
      float4 bv = make_float4(0.f, 0.f, 0.f, 0.f);
      if (n0 + c4 < N) bv = *(const float4*)(B + (kb + row) * N + n0 + c4);
      Bs[row][c4+0]=bv.x; Bs[row][c4+1]=bv.y; Bs[row][c4+2]=bv.z; Bs[row][c4+3]=bv.w;
    }
    __syncthreads();
    #pragma unroll
    for (int kk = 0; kk < 16; kk++) {
      float a_[4], b_[4];
      #pragma unroll
      for (int i = 0; i < 4; i++) a_[i] = As[ty * 4 + i][kk];
      #pragma unroll
      for (int j = 0; j < 4; j++) b_[j] = Bs[kk][tx * 4 + j];
      #pragma unroll
      for (int i = 0; i < 4; i++)
        for (int j = 0; j < 4; j++)
          acc[i][j] = fmaf(a_[i], b_[j], acc[i][j]);
    }
    __syncthreads();
  }
  #pragma unroll
  for (int i = 0; i < 4; i++) {
    int row = m0 + ty * 4 + i;
    #pragma unroll
    for (int j = 0; j < 4; j++) {
      int col = n0 + tx * 4 + j;
      if (col < N) {
        float val = acc[i][j] + bias[col];
        if (ACT == 0) val = val > 0.f ? val : 0.f;
        else          val = 1.f / (1.f + expf(-val));
        C[row * N + col] = val;
      }
    }
  }
}

// ===========================================================================
extern "C" void kernel_launch(void* const* d_in, const int* in_sizes, int n_in,
                              void* d_out, int out_size, void* d_ws, size_t ws_size,
                              hipStream_t stream)
{
  const float* data = (const float*)d_in[0];
  const float* w1   = (const float*)d_in[1];
  const float* b1   = (const float*)d_in[2];
  const float* pw   = (const float*)d_in[3];
  const float* pb   = (const float*)d_in[4];
  const float* Wdc  = (const float*)d_in[5];
  const float* dw1  = (const float*)d_in[6];
  const float* db1  = (const float*)d_in[7];
  const float* dw2  = (const float*)d_in[8];
  const float* db2  = (const float*)d_in[9];
  const float* dw3  = (const float*)d_in[10];
  const float* db3  = (const float*)d_in[11];

  float* out     = (float*)d_out;
  float* outp    = out;              // [256][10][16][1]
  float* recon   = out + 40960;      // [256][784]
  float* maskedo = out + 241664;     // [256][10]

  char* wsb = (char*)d_ws;
  // big section (conv phase)
  unsigned short* x1h = (unsigned short*)(wsb);               // 52,428,800 B
  unsigned short* x1l = (unsigned short*)(wsb + 52428800);    // 52,428,800
  unsigned short* wbh = (unsigned short*)(wsb + 104857600);   // 10,616,832
  unsigned short* wbl = (unsigned short*)(wsb + 115474432);   // 10,616,832
  float*  Wrt  = (float*)(wsb + 126091264);                   //  5,898,240
  float*  part = (float*)(wsb + 131989504);                   // 28,311,552
  // overlay section (x1h region is dead after conv2)
  float* u    = (float*)(wsb);
  float* uT   = (float*)(wsb + 9437184);
  float* vT   = (float*)(wsb + 18874368);
  float* bij  = (float*)(wsb + 19038208);
  float* cij  = (float*)(wsb + 19084288);
  float* sbuf = (float*)(wsb + 19130368);
  float* vbuf = (float*)(wsb + 19294208);
  float* norms= (float*)(wsb + 19458048);
  float* score= (float*)(wsb + 19468288);
  float* tbuf = (float*)(wsb + 19478528);
  float* h1   = (float*)(wsb + 19642368);
  float* h2   = (float*)(wsb + 20166656);

  conv1_kernel<<<1024, 320, 0, stream>>>(data, w1, b1, x1h, x1l);
  wprep<<<256, 256, 0, stream>>>(pw, wbh, wbl);
  wprep2<<<5760, 256, 0, stream>>>(Wdc, Wrt);
  conv2_mfma<<<432, 256, 81920, stream>>>(x1h, x1l, wbh, wbl, part);
  combine_squash<<<1152, 256, 0, stream>>>(part, pb, u, uT);

  // routing iteration 0 (b_ij = 0 -> uniform c); b_ij assigned, not added
  s_pass<<<640, 256, 0, stream>>>(u, Wrt, cij, sbuf, 1);
  squash_v<<<10, 256, 0, stream>>>(sbuf, vbuf, vT, outp, norms, 0);
  a_pass<<<1152, 256, 0, stream>>>(uT, Wdc, vT, bij, 1);
  // iteration 1
  route_softmax<<<10, 256, 0, stream>>>(bij, cij);
  s_pass<<<640, 256, 0, stream>>>(u, Wrt, cij, sbuf, 0);
  squash_v<<<10, 256, 0, stream>>>(sbuf, vbuf, vT, outp, norms, 0);
  a_pass<<<1152, 256, 0, stream>>>(uT, Wdc, vT, bij, 0);
  // iteration 2 (final)
  route_softmax<<<10, 256, 0, stream>>>(bij, cij);
  s_pass<<<640, 256, 0, stream>>>(u, Wrt, cij, sbuf, 0);
  squash_v<<<10, 256, 0, stream>>>(sbuf, vbuf, vT, outp, norms, 1);

  // decoder
  batch_softmax<<<10, 256, 0, stream>>>(norms, score);
  mask_t_kernel<<<1, 256, 0, stream>>>(score, vbuf, maskedo, tbuf);
  gemm_act<0><<<dim3(8, 4),  256, 0, stream>>>(tbuf, dw1, db1, h1,    256, 512,  160);
  gemm_act<0><<<dim3(16, 4), 256, 0, stream>>>(h1,   dw2, db2, h2,    256, 1024, 512);
  gemm_act<1><<<dim3(13, 4), 256, 0, stream>>>(h2,   dw3, db3, recon, 256, 784,  1024);
}

// Round 3
// 891.456 us; speedup vs baseline: 4.1281x; 2.0428x over previous
//
#include <hip/hip_runtime.h>
#include <math.h>

// ---------------------------------------------------------------------------
// CapsNet forward.  conv1 fp32 -> split to bf16(hi,lo) channel-last ->
// conv2 as implicit-GEMM MFMA (bf16x2 compensated, fp32 accum) ->
// squash -> routing (coalesced layouts) -> decoder MLP (fp32).
// ---------------------------------------------------------------------------

typedef __attribute__((ext_vector_type(8))) short short8;
typedef __attribute__((ext_vector_type(4))) float f32x4;

__device__ __forceinline__ unsigned short f2bf(float x) {
  unsigned int u = __float_as_uint(x);
  unsigned int r = (u + 0x7fffu + ((u >> 16) & 1u)) >> 16;
  return (unsigned short)r;
}
__device__ __forceinline__ float bf2f(unsigned short h) {
  return __uint_as_float(((unsigned int)h) << 16);
}
__device__ __forceinline__ void gload16(const void* g, void* l) {
  __builtin_amdgcn_global_load_lds(
      (const __attribute__((address_space(1))) unsigned int*)g,
      (__attribute__((address_space(3))) unsigned int*)l, 16, 0, 0);
}
__device__ __forceinline__ float dot8(const float* w, float4 a, float4 b) {
  return w[0]*a.x + w[1]*a.y + w[2]*a.z + w[3]*a.w +
         w[4]*b.x + w[5]*b.y + w[6]*b.z + w[7]*b.w;
}

// ======================= conv1: [256,1,28,28] -> bf16x2 CL [256,20,20,256] ==
// grid 1024 = 256 b x 4 co-groups(64 co); block 320 = 16 co-quads x 20 oy
__global__ __launch_bounds__(320) void conv1_kernel(
    const float* __restrict__ data, const float* __restrict__ w1,
    const float* __restrict__ b1, unsigned short* __restrict__ xh,
    unsigned short* __restrict__ xl)
{
  const int bid = blockIdx.x;
  const int b   = bid >> 2;
  const int cog = bid & 3;
  __shared__ float img[784];
  __shared__ float wsm[81][64];
  const int t = threadIdx.x;
  for (int i = t; i < 784; i += 320) img[i] = data[b * 784 + i];
  for (int i = t; i < 64 * 81; i += 320) {
    int col = i / 81, k = i % 81;
    wsm[k][col] = w1[(cog * 64 + col) * 81 + k];
  }
  __syncthreads();
  const int cg = t & 15;
  const int oy = t >> 4;           // 0..19
  const int co0 = cog * 64 + cg * 4;
  float acc[4][20];
  #pragma unroll
  for (int i = 0; i < 4; i++) {
    float bv = b1[co0 + i];
    #pragma unroll
    for (int j = 0; j < 20; j++) acc[i][j] = bv;
  }
  for (int ky = 0; ky < 9; ky++) {
    float xr[28];
    const float4* rp = reinterpret_cast<const float4*>(&img[(oy + ky) * 28]);
    #pragma unroll
    for (int q = 0; q < 7; q++) {
      float4 v4 = rp[q];
      xr[q*4+0] = v4.x; xr[q*4+1] = v4.y; xr[q*4+2] = v4.z; xr[q*4+3] = v4.w;
    }
    #pragma unroll
    for (int kx = 0; kx < 9; kx++) {
      float4 wv = *reinterpret_cast<const float4*>(&wsm[ky * 9 + kx][cg * 4]);
      #pragma unroll
      for (int ox = 0; ox < 20; ox++) {
        float xv = xr[ox + kx];
        acc[0][ox] = fmaf(xv, wv.x, acc[0][ox]);
        acc[1][ox] = fmaf(xv, wv.y, acc[1][ox]);
        acc[2][ox] = fmaf(xv, wv.z, acc[2][ox]);
        acc[3][ox] = fmaf(xv, wv.w, acc[3][ox]);
      }
    }
  }
  #pragma unroll
  for (int ox = 0; ox < 20; ox++) {
    ushort4 hv, lv;
    float v0 = fmaxf(acc[0][ox], 0.f), v1 = fmaxf(acc[1][ox], 0.f);
    float v2 = fmaxf(acc[2][ox], 0.f), v3 = fmaxf(acc[3][ox], 0.f);
    hv.x = f2bf(v0); lv.x = f2bf(v0 - bf2f(hv.x));
    hv.y = f2bf(v1); lv.y = f2bf(v1 - bf2f(hv.y));
    hv.z = f2bf(v2); lv.z = f2bf(v2 - bf2f(hv.z));
    hv.w = f2bf(v3); lv.w = f2bf(v3 - bf2f(hv.w));
    const int pix = (b * 20 + oy) * 20 + ox;
    *(ushort4*)(xh + pix * 256 + co0) = hv;
    *(ushort4*)(xl + pix * 256 + co0) = lv;
  }
}

// ===== conv2 weight prep: pw[co][ci][81] fp32 -> w[k][co][ci] bf16 hi/lo ====
// grid 256 (co); block 256 (ci); LDS-staged so global reads+writes coalesce
__global__ void wprep(const float* __restrict__ pw, unsigned short* __restrict__ wh,
                      unsigned short* __restrict__ wl)
{
  const int co = blockIdx.x;
  const int t  = threadIdx.x;
  __shared__ float slab[20736];   // [ci][81] for this co
  for (int i = t; i < 20736; i += 256) slab[i] = pw[co * 20736 + i];
  __syncthreads();
  for (int k = 0; k < 81; k++) {
    float x = slab[t * 81 + k];
    unsigned short h = f2bf(x);
    wh[(k * 256 + co) * 256 + t] = h;
    wl[(k * 256 + co) * 256 + t] = f2bf(x - bf2f(h));
  }
}

// ===== routing weight prep: Wdc[r][c][o][8] -> Wrt[c][o][r][8] ==============
__global__ void wprep2(const float* __restrict__ Wdc, float* __restrict__ Wrt)
{
  const int id = blockIdx.x * 256 + threadIdx.x;   // < 1,474,560
  const int i = id & 7;
  const int o = (id >> 3) & 15;
  const int rc = id >> 7;
  const int c = rc % 10, r = rc / 10;
  Wrt[((c * 16 + o) * 1152 + r) * 8 + i] = Wdc[id];
}

// ===== conv2 MFMA: M=64 pix x N=256 co, K=32-ci chunks, 3-way ky split ======
// grid 432 = 144 m-tiles x 3 ky-groups; block 256 (4 waves); 80KB dynamic LDS
__global__ __launch_bounds__(256) void conv2_mfma(
    const unsigned short* __restrict__ xh, const unsigned short* __restrict__ xl,
    const unsigned short* __restrict__ wh, const unsigned short* __restrict__ wl,
    float* __restrict__ part)
{
  extern __shared__ char lds[];
  const int t   = threadIdx.x;
  const int blk = blockIdx.x;
  const int mt  = blk % 144;
  const int kg  = blk / 144;
  const int m0  = mt * 64;
  const int lane = t & 63;
  const int w    = t >> 6;
  const int l15  = lane & 15, l4 = lane >> 4;
  const int n0   = w * 64;

  // A staging address precompute: thread t -> (pix row = t>>2, ci-oct = t&3)
  const int arow = t >> 2, aoct = t & 3;
  const int apix = m0 + arow;
  const int ab  = apix / 36;
  const int asp = apix - ab * 36;
  const int aoy = asp / 6;
  const int aox = asp - aoy * 6;
  const int abase = ((ab * 20 + 2 * aoy) * 20 + 2 * aox) * 256 + aoct * 8;
  // B staging: iter i covers co = i*64 + (t>>2), oct = t&3
  const int bofs0 = (t >> 2) * 256 + (t & 3) * 8;

  f32x4 acc[4][4];
  #pragma unroll
  for (int i = 0; i < 4; i++)
    #pragma unroll
    for (int j = 0; j < 4; j++) acc[i][j] = (f32x4){0.f, 0.f, 0.f, 0.f};

  const int ky0 = kg * 3;

  auto stage = [&](int buf, int ky, int kx, int ci0) {
    char* base = lds + buf * 40960;
    const int axy = (ky * 20 + kx) * 256;
    const int wxy = (ky * 9 + kx) * 65536;
    gload16(xh + abase + axy + ci0, base + t * 16);
    gload16(xl + abase + axy + ci0, base + 4096 + t * 16);
    const unsigned short* wph = wh + wxy + ci0 + bofs0;
    const unsigned short* wpl = wl + wxy + ci0 + bofs0;
    char* bhd = base + 8192  + t * 16;
    char* bld = base + 24576 + t * 16;
    #pragma unroll
    for (int i = 0; i < 4; i++) {
      gload16(wph + i * 16384, bhd + i * 4096);
      gload16(wpl + i * 16384, bld + i * 4096);
    }
  };

  stage(0, ky0, 0, 0);
  __syncthreads();

  int kyn = ky0, kxn = 0, ccn = 0;
  #pragma unroll 1
  for (int s = 0; s < 216; ++s) {
    const int cur = s & 1;
    ccn++;
    if (ccn == 8) { ccn = 0; kxn++; if (kxn == 9) { kxn = 0; kyn++; } }
    if (s < 215) stage(cur ^ 1, kyn, kxn, ccn * 32);

    char* base = lds + cur * 40960;
    short8 a_h[4], a_l[4], b_h[4], b_l[4];
    #pragma unroll
    for (int mf = 0; mf < 4; mf++) {
      const int off = ((mf * 16 + l15) << 6) + (l4 << 4);
      a_h[mf] = *(const short8*)(base + off);
      a_l[mf] = *(const short8*)(base + 4096 + off);
    }
    #pragma unroll
    for (int nf = 0; nf < 4; nf++) {
      const int off = ((nf * 16 + l15) << 6) + (l4 << 4);
      b_h[nf] = *(const short8*)(base + 8192  + (n0 << 6) + off);
      b_l[nf] = *(const short8*)(base + 24576 + (n0 << 6) + off);
    }
    #pragma unroll
    for (int mf = 0; mf < 4; mf++)
      #pragma unroll
      for (int nf = 0; nf < 4; nf++) {
        acc[mf][nf] = __builtin_amdgcn_mfma_f32_16x16x32_bf16(a_h[mf], b_h[nf], acc[mf][nf], 0, 0, 0);
        acc[mf][nf] = __builtin_amdgcn_mfma_f32_16x16x32_bf16(a_l[mf], b_h[nf], acc[mf][nf], 0, 0, 0);
        acc[mf][nf] = __builtin_amdgcn_mfma_f32_16x16x32_bf16(a_h[mf], b_l[nf], acc[mf][nf], 0, 0, 0);
      }
    __syncthreads();
  }

  // epilogue: C[row=pix][col=co]; lane holds col=l15, rows l4*4+reg
  float* pout = part + kg * 2359296;
  #pragma unroll
  for (int mf = 0; mf < 4; mf++) {
    #pragma unroll
    for (int reg = 0; reg < 4; reg++) {
      const int pix = m0 + mf * 16 + l4 * 4 + reg;
      const int b  = pix / 36;
      const int sp = pix - b * 36;
      float* pb_ = pout + b * 9216 + sp;
      #pragma unroll
      for (int nf = 0; nf < 4; nf++) {
        const int co = n0 + nf * 16 + l15;
        pb_[co * 36] = acc[mf][nf][reg];
      }
    }
  }
}

// ======== combine 3 split-K partials + bias, squash(8); emit u and u_T ======
__global__ void combine_squash(const float* __restrict__ part,
                               const float* __restrict__ pb,
                               float* __restrict__ u, float* __restrict__ uT)
{
  const int id = blockIdx.x * 256 + threadIdx.x;  // 0..294911
  const int b = id / 1152;
  const int r = id % 1152;
  const float* p0 = part + b * 9216 + r * 8;
  float v[8];
  #pragma unroll
  for (int i = 0; i < 8; i++) v[i] = p0[i] + p0[2359296 + i] + p0[4718592 + i];
  #pragma unroll
  for (int i = 0; i < 8; i++) v[i] += pb[(r * 8 + i) / 36];
  float sq = 0.f;
  #pragma unroll
  for (int i = 0; i < 8; i++) sq += v[i] * v[i];
  float scale = sq / ((1.f + sq) * sqrtf(sq));
  #pragma unroll
  for (int i = 0; i < 8; i++) {
    float o = v[i] * scale;
    u[b * 9216 + r * 8 + i] = o;
    uT[(r * 256 + b) * 8 + i] = o;
  }
}

// ================== softmax over routes (per class column) ==================
__global__ void route_softmax(const float* __restrict__ bij, float* __restrict__ cij)
{
  const int c = blockIdx.x;
  const int t = threadIdx.x;
  __shared__ float red[8];
  float m = -1e30f;
  for (int r = t; r < 1152; r += 256) m = fmaxf(m, bij[c * 1152 + r]);
  for (int off = 32; off; off >>= 1) m = fmaxf(m, __shfl_down(m, off, 64));
  if ((t & 63) == 0) red[t >> 6] = m;
  __syncthreads();
  m = fmaxf(fmaxf(red[0], red[1]), fmaxf(red[2], red[3]));
  float s = 0.f;
  for (int r = t; r < 1152; r += 256) {
    float e = expf(bij[c * 1152 + r] - m);
    cij[c * 1152 + r] = e;
    s += e;
  }
  for (int off = 32; off; off >>= 1) s += __shfl_down(s, off, 64);
  if ((t & 63) == 0) red[4 + (t >> 6)] = s;
  __syncthreads();
  float inv = 1.f / (red[4] + red[5] + red[6] + red[7]);
  for (int r = t; r < 1152; r += 256) cij[c * 1152 + r] *= inv;
}

// ===== s_j[b,c,o] = sum_r c[r,c] * dot(W[r,c,o,:], u[b,r,:])  (Wrt layout) ==
__global__ __launch_bounds__(256) void s_pass(
    const float* __restrict__ u, const float* __restrict__ Wrt,
    const float* __restrict__ cij, float* __restrict__ s, int uniform)
{
  const int c  = blockIdx.x % 10;
  const int b0 = (blockIdx.x / 10) * 4;
  const int t  = threadIdx.x;
  float acc[4][16];
  #pragma unroll
  for (int bb = 0; bb < 4; bb++)
    #pragma unroll
    for (int o = 0; o < 16; o++) acc[bb][o] = 0.f;
  #pragma unroll 1
  for (int r = t; r < 1152; r += 256) {
    float cw = uniform ? (1.f / 1152.f) : cij[c * 1152 + r];
    float4 ua[4], ub[4];
    #pragma unroll
    for (int bb = 0; bb < 4; bb++) {
      const float4* up = (const float4*)(u + (b0 + bb) * 9216 + r * 8);
      float4 x0 = up[0], x1 = up[1];
      ua[bb] = make_float4(x0.x*cw, x0.y*cw, x0.z*cw, x0.w*cw);
      ub[bb] = make_float4(x1.x*cw, x1.y*cw, x1.z*cw, x1.w*cw);
    }
    const float* wbase = Wrt + c * 147456 + r * 8;
    #pragma unroll
    for (int o = 0; o < 16; o++) {
      float4 wa = *(const float4*)(wbase + o * 9216);
      float4 wb = *(const float4*)(wbase + o * 9216 + 4);
      #pragma unroll
      for (int bb = 0; bb < 4; bb++)
        acc[bb][o] += wa.x*ua[bb].x + wa.y*ua[bb].y + wa.z*ua[bb].z + wa.w*ua[bb].w
                    + wb.x*ub[bb].x + wb.y*ub[bb].y + wb.z*ub[bb].z + wb.w*ub[bb].w;
    }
  }
  __shared__ float lred[4][64];
  const int lane = t & 63, wid = t >> 6;
  #pragma unroll
  for (int bb = 0; bb < 4; bb++)
    #pragma unroll
    for (int o = 0; o < 16; o++) {
      float val = acc[bb][o];
      for (int off = 32; off; off >>= 1) val += __shfl_down(val, off, 64);
      if (lane == 0) lred[wid][bb * 16 + o] = val;
    }
  __syncthreads();
  if (t < 64) {
    float v = lred[0][t] + lred[1][t] + lred[2][t] + lred[3][t];
    int bb = t >> 4, o = t & 15;
    s[(b0 + bb) * 160 + c * 16 + o] = v;
  }
}

// ======================== v = squash(s); emit v, v_T, outp, norms ===========
__global__ void squash_v(const float* __restrict__ s, float* __restrict__ v,
                         float* __restrict__ vT, float* __restrict__ outp,
                         float* __restrict__ norms, int final_it)
{
  const int id = blockIdx.x * 256 + threadIdx.x;  // b*10+c
  const int b = id / 10, c = id - b * 10;
  const float4* sp = (const float4*)(s + id * 16);
  float x[16];
  #pragma unroll
  for (int q = 0; q < 4; q++) {
    float4 v4 = sp[q];
    x[q*4+0]=v4.x; x[q*4+1]=v4.y; x[q*4+2]=v4.z; x[q*4+3]=v4.w;
  }
  float sq = 0.f;
  #pragma unroll
  for (int k = 0; k < 16; k++) sq += x[k] * x[k];
  float nrm = sqrtf(sq);
  float scale = sq / ((1.f + sq) * nrm);
  #pragma unroll
  for (int k = 0; k < 16; k++) {
    float vv = x[k] * scale;
    v[id * 16 + k] = vv;
    vT[(c * 256 + b) * 16 + k] = vv;
    if (final_it) outp[id * 16 + k] = vv;
  }
  if (final_it) norms[id] = scale * nrm;
}

// == a[r,c] = (1/B) sum_{b,o} dot(W[r,c,o],u[b,r]) * v[b,c,o]; bij (+)= a ====
// grid 1152 (r); block 256 (thread = b).  Class loop NOT unrolled: keeps the
// live set ~30 VGPR (round-2 version spilled: 256 VGPR, 925MB scratch writes).
__global__ __launch_bounds__(256) void a_pass(
    const float* __restrict__ uT, const float* __restrict__ W,
    const float* __restrict__ vT, float* __restrict__ bij, int assign)
{
  const int r = blockIdx.x;
  const int t = threadIdx.x;
  __shared__ float wsl[1280];
  __shared__ float lred[4][10];
  for (int i = t; i < 1280; i += 256) wsl[i] = W[r * 1280 + i];
  __syncthreads();
  const float4* up = (const float4*)(uT + (r * 256 + t) * 8);
  float4 ua = up[0], ub = up[1];
  const int lane = t & 63, wid = t >> 6;
  #pragma unroll 1
  for (int c = 0; c < 10; c++) {
    const float* wc = &wsl[c * 128];
    const float4* vp = (const float4*)(vT + (c * 256 + t) * 16);
    float p = 0.f;
    #pragma unroll
    for (int q = 0; q < 4; q++) {
      float4 vq = vp[q];
      p += dot8(wc + (q * 4 + 0) * 8, ua, ub) * vq.x;
      p += dot8(wc + (q * 4 + 1) * 8, ua, ub) * vq.y;
      p += dot8(wc + (q * 4 + 2) * 8, ua, ub) * vq.z;
      p += dot8(wc + (q * 4 + 3) * 8, ua, ub) * vq.w;
    }
    for (int off = 32; off; off >>= 1) p += __shfl_down(p, off, 64);
    if (lane == 0) lred[wid][c] = p;
  }
  __syncthreads();
  if (t < 10) {
    float a = (lred[0][t] + lred[1][t] + lred[2][t] + lred[3][t]) * (1.f / 256.f);
    float o = assign ? 0.f : bij[t * 1152 + r];
    bij[t * 1152 + r] = o + a;
  }
}

// ================= softmax of class norms over the batch axis ===============
__global__ void batch_softmax(const float* __restrict__ norms, float* __restrict__ scores)
{
  const int c = blockIdx.x;
  const int t = threadIdx.x;
  __shared__ float red[8];
  float x = norms[t * 10 + c];
  float m = x;
  for (int off = 32; off; off >>= 1) m = fmaxf(m, __shfl_down(m, off, 64));
  if ((t & 63) == 0) red[t >> 6] = m;
  __syncthreads();
  m = fmaxf(fmaxf(red[0], red[1]), fmaxf(red[2], red[3]));
  float e = expf(x - m);
  float ssum = e;
  for (int off = 32; off; off >>= 1) ssum += __shfl_down(ssum, off, 64);
  if ((t & 63) == 0) red[4 + (t >> 6)] = ssum;
  __syncthreads();
  scores[t * 10 + c] = e / (red[4] + red[5] + red[6] + red[7]);
}

// ============ argmax over classes, one-hot mask, masked t vector ============
__global__ void mask_t_kernel(const float* __restrict__ scores, const float* __restrict__ v,
                              float* __restrict__ masked, float* __restrict__ tbuf)
{
  const int b = threadIdx.x;
  float best = scores[b * 10];
  int idx = 0;
  for (int c = 1; c < 10; c++) {
    float sc = scores[b * 10 + c];
    if (sc > best) { best = sc; idx = c; }
  }
  for (int c = 0; c < 10; c++) {
    float msk = (c == idx) ? 1.f : 0.f;
    masked[b * 10 + c] = msk;
    for (int o = 0; o < 16; o++)
      tbuf[b * 160 + c * 16 + o] = v[b * 160 + c * 16 + o] * msk;
  }
}

// ==================== small GEMM: C = act(A[M,K] @ B[K,N] + bias) ===========
template <int ACT>
__global__ __launch_bounds__(256) void gemm_act(
    const float* __restrict__ A, const float* __restrict__ B,
    const float* __restrict__ bias, float* __restrict__ C, int M, int N, int K)
{
  __shared__ float As[64][17];
  __shared__ float Bs[16][64];
  const int t = threadIdx.x;
  const int tx = t & 15, ty = t >> 4;
  const int m0 = blockIdx.y * 64, n0 = blockIdx.x * 64;
  float acc[4][4] = {};
  for (int kb = 0; kb < K; kb += 16) {
    {
      int row = t >> 2, c4 = (t & 3) * 4;
      float4 av = *(const float4*)(A + (m0 + row) * K + kb + c4);
      As[row][c4+0]=av.x; As[row][c4+1]=av.y; As[row][c4+2]=av.z; As[row][c4+3]=av.w;
    }
    {
      int row = t >> 4, c4 = (t & 15) * 4;
      float4 bv = make_float4(0.f, 0.f, 0.f, 0.f);
      if (n0 + c4 < N) bv = *(const float4*)(B + (kb + row) * N + n0 + c4);
      Bs[row][c4+0]=bv.x; Bs[row][c4+1]=bv.y; Bs[row][c4+2]=bv.z; Bs[row][c4+3]=bv.w;
    }
    __syncthreads();
    #pragma unroll
    for (int kk = 0; kk < 16; kk++) {
      float a_[4], b_[4];
      #pragma unroll
      for (int i = 0; i < 4; i++) a_[i] = As[ty * 4 + i][kk];
      #pragma unroll
      for (int j = 0; j < 4; j++) b_[j] = Bs[kk][tx * 4 + j];
      #pragma unroll
      for (int i = 0; i < 4; i++)
        for (int j = 0; j < 4; j++)
          acc[i][j] = fmaf(a_[i], b_[j], acc[i][j]);
    }
    __syncthreads();
  }
  #pragma unroll
  for (int i = 0; i < 4; i++) {
    int row = m0 + ty * 4 + i;
    #pragma unroll
    for (int j = 0; j < 4; j++) {
      int col = n0 + tx * 4 + j;
      if (col < N) {
        float val = acc[i][j] + bias[col];
        if (ACT == 0) val = val > 0.f ? val : 0.f;
        else          val = 1.f / (1.f + expf(-val));
        C[row * N + col] = val;
      }
    }
  }
}

// ===========================================================================
extern "C" void kernel_launch(void* const* d_in, const int* in_sizes, int n_in,
                              void* d_out, int out_size, void* d_ws, size_t ws_size,
                              hipStream_t stream)
{
  const float* data = (const float*)d_in[0];
  const float* w1   = (const float*)d_in[1];
  const float* b1   = (const float*)d_in[2];
  const float* pw   = (const float*)d_in[3];
  const float* pb   = (const float*)d_in[4];
  const float* Wdc  = (const float*)d_in[5];
  const float* dw1  = (const float*)d_in[6];
  const float* db1  = (const float*)d_in[7];
  const float* dw2  = (const float*)d_in[8];
  const float* db2  = (const float*)d_in[9];
  const float* dw3  = (const float*)d_in[10];
  const float* db3  = (const float*)d_in[11];

  float* out     = (float*)d_out;
  float* outp    = out;              // [256][10][16][1]
  float* recon   = out + 40960;      // [256][784]
  float* maskedo = out + 241664;     // [256][10]

  char* wsb = (char*)d_ws;
  // big section (conv phase)
  unsigned short* x1h = (unsigned short*)(wsb);               // 52,428,800 B
  unsigned short* x1l = (unsigned short*)(wsb + 52428800);    // 52,428,800
  unsigned short* wbh = (unsigned short*)(wsb + 104857600);   // 10,616,832
  unsigned short* wbl = (unsigned short*)(wsb + 115474432);   // 10,616,832
  float*  Wrt  = (float*)(wsb + 126091264);                   //  5,898,240
  float*  part = (float*)(wsb + 131989504);                   // 28,311,552
  // overlay section (x1h region is dead after conv2)
  float* u    = (float*)(wsb);
  float* uT   = (float*)(wsb + 9437184);
  float* vT   = (float*)(wsb + 18874368);
  float* bij  = (float*)(wsb + 19038208);
  float* cij  = (float*)(wsb + 19084288);
  float* sbuf = (float*)(wsb + 19130368);
  float* vbuf = (float*)(wsb + 19294208);
  float* norms= (float*)(wsb + 19458048);
  float* score= (float*)(wsb + 19468288);
  float* tbuf = (float*)(wsb + 19478528);
  float* h1   = (float*)(wsb + 19642368);
  float* h2   = (float*)(wsb + 20166656);

  conv1_kernel<<<1024, 320, 0, stream>>>(data, w1, b1, x1h, x1l);
  wprep<<<256, 256, 0, stream>>>(pw, wbh, wbl);
  wprep2<<<5760, 256, 0, stream>>>(Wdc, Wrt);
  conv2_mfma<<<432, 256, 81920, stream>>>(x1h, x1l, wbh, wbl, part);
  combine_squash<<<1152, 256, 0, stream>>>(part, pb, u, uT);

  // routing iteration 0 (b_ij = 0 -> uniform c); b_ij assigned, not added
  s_pass<<<640, 256, 0, stream>>>(u, Wrt, cij, sbuf, 1);
  squash_v<<<10, 256, 0, stream>>>(sbuf, vbuf, vT, outp, norms, 0);
  a_pass<<<1152, 256, 0, stream>>>(uT, Wdc, vT, bij, 1);
  // iteration 1
  route_softmax<<<10, 256, 0, stream>>>(bij, cij);
  s_pass<<<640, 256, 0, stream>>>(u, Wrt, cij, sbuf, 0);
  squash_v<<<10, 256, 0, stream>>>(sbuf, vbuf, vT, outp, norms, 0);
  a_pass<<<1152, 256, 0, stream>>>(uT, Wdc, vT, bij, 0);
  // iteration 2 (final)
  route_softmax<<<10, 256, 0, stream>>>(bij, cij);
  s_pass<<<640, 256, 0, stream>>>(u, Wrt, cij, sbuf, 0);
  squash_v<<<10, 256, 0, stream>>>(sbuf, vbuf, vT, outp, norms, 1);

  // decoder
  batch_softmax<<<10, 256, 0, stream>>>(norms, score);
  mask_t_kernel<<<1, 256, 0, stream>>>(score, vbuf, maskedo, tbuf);
  gemm_act<0><<<dim3(8, 4),  256, 0, stream>>>(tbuf, dw1, db1, h1,    256, 512,  160);
  gemm_act<0><<<dim3(16, 4), 256, 0, stream>>>(h1,   dw2, db2, h2,    256, 1024, 512);
  gemm_act<1><<<dim3(13, 4), 256, 0, stream>>>(h2,   dw3, db3, recon, 256, 784,  1024);
}

// Round 4
// 857.730 us; speedup vs baseline: 4.2904x; 1.0393x over previous
//
#include <hip/hip_runtime.h>
#include <math.h>

// ---------------------------------------------------------------------------
// CapsNet forward.  conv1 fp32 -> bf16(hi,lo) channel-last -> conv2 as
// implicit-GEMM MFMA 32x32x16 (bf16x2 compensated, fp32 accum, counted-vmcnt
// pipeline + swizzled LDS) -> squash -> routing (W-chunk LDS s_pass, inline
// route softmax) -> fused finalize -> decoder MLP (fp32).
// ---------------------------------------------------------------------------

typedef __attribute__((ext_vector_type(8))) short short8;
typedef __attribute__((ext_vector_type(16))) float f32x16;

__device__ __forceinline__ unsigned short f2bf(float x) {
  unsigned int u = __float_as_uint(x);
  unsigned int r = (u + 0x7fffu + ((u >> 16) & 1u)) >> 16;
  return (unsigned short)r;
}
__device__ __forceinline__ float bf2f(unsigned short h) {
  return __uint_as_float(((unsigned int)h) << 16);
}
__device__ __forceinline__ void gload16(const void* g, void* l) {
  __builtin_amdgcn_global_load_lds(
      (const __attribute__((address_space(1))) unsigned int*)g,
      (__attribute__((address_space(3))) unsigned int*)l, 16, 0, 0);
}
__device__ __forceinline__ float dot8(const float* w, float4 a, float4 b) {
  return w[0]*a.x + w[1]*a.y + w[2]*a.z + w[3]*a.w +
         w[4]*b.x + w[5]*b.y + w[6]*b.z + w[7]*b.w;
}

// ======================= conv1: [256,1,28,28] -> bf16x2 CL [256,20,20,256] ==
// grid 1024 = 256 b x 4 co-groups(64 co); block 320 = 16 co-quads x 20 oy
__global__ __launch_bounds__(320) void conv1_kernel(
    const float* __restrict__ data, const float* __restrict__ w1,
    const float* __restrict__ b1, unsigned short* __restrict__ xh,
    unsigned short* __restrict__ xl)
{
  const int bid = blockIdx.x;
  const int b   = bid >> 2;
  const int cog = bid & 3;
  __shared__ float img[784];
  __shared__ float wsm[81][64];
  const int t = threadIdx.x;
  for (int i = t; i < 784; i += 320) img[i] = data[b * 784 + i];
  for (int i = t; i < 64 * 81; i += 320) {
    int col = i / 81, k = i % 81;
    wsm[k][col] = w1[(cog * 64 + col) * 81 + k];
  }
  __syncthreads();
  const int cg = t & 15;
  const int oy = t >> 4;           // 0..19
  const int co0 = cog * 64 + cg * 4;
  float acc[4][20];
  #pragma unroll
  for (int i = 0; i < 4; i++) {
    float bv = b1[co0 + i];
    #pragma unroll
    for (int j = 0; j < 20; j++) acc[i][j] = bv;
  }
  for (int ky = 0; ky < 9; ky++) {
    float xr[28];
    const float4* rp = reinterpret_cast<const float4*>(&img[(oy + ky) * 28]);
    #pragma unroll
    for (int q = 0; q < 7; q++) {
      float4 v4 = rp[q];
      xr[q*4+0] = v4.x; xr[q*4+1] = v4.y; xr[q*4+2] = v4.z; xr[q*4+3] = v4.w;
    }
    #pragma unroll
    for (int kx = 0; kx < 9; kx++) {
      float4 wv = *reinterpret_cast<const float4*>(&wsm[ky * 9 + kx][cg * 4]);
      #pragma unroll
      for (int ox = 0; ox < 20; ox++) {
        float xv = xr[ox + kx];
        acc[0][ox] = fmaf(xv, wv.x, acc[0][ox]);
        acc[1][ox] = fmaf(xv, wv.y, acc[1][ox]);
        acc[2][ox] = fmaf(xv, wv.z, acc[2][ox]);
        acc[3][ox] = fmaf(xv, wv.w, acc[3][ox]);
      }
    }
  }
  #pragma unroll
  for (int ox = 0; ox < 20; ox++) {
    ushort4 hv, lv;
    float v0 = fmaxf(acc[0][ox], 0.f), v1 = fmaxf(acc[1][ox], 0.f);
    float v2 = fmaxf(acc[2][ox], 0.f), v3 = fmaxf(acc[3][ox], 0.f);
    hv.x = f2bf(v0); lv.x = f2bf(v0 - bf2f(hv.x));
    hv.y = f2bf(v1); lv.y = f2bf(v1 - bf2f(hv.y));
    hv.z = f2bf(v2); lv.z = f2bf(v2 - bf2f(hv.z));
    hv.w = f2bf(v3); lv.w = f2bf(v3 - bf2f(hv.w));
    const int pix = (b * 20 + oy) * 20 + ox;
    *(ushort4*)(xh + pix * 256 + co0) = hv;
    *(ushort4*)(xl + pix * 256 + co0) = lv;
  }
}

// ===== conv2 weight prep: pw[co][ci][81] fp32 -> w[k][co][ci] bf16 hi/lo ====
__global__ void wprep(const float* __restrict__ pw, unsigned short* __restrict__ wh,
                      unsigned short* __restrict__ wl)
{
  const int co = blockIdx.x;
  const int t  = threadIdx.x;
  __shared__ float slab[20736];   // [ci][81] for this co
  for (int i = t; i < 20736; i += 256) slab[i] = pw[co * 20736 + i];
  __syncthreads();
  for (int k = 0; k < 81; k++) {
    float x = slab[t * 81 + k];
    unsigned short h = f2bf(x);
    wh[(k * 256 + co) * 256 + t] = h;
    wl[(k * 256 + co) * 256 + t] = f2bf(x - bf2f(h));
  }
}

// ===== conv2 MFMA 32x32x16: M=64 pix x N=256 co, 3-way ky split-K ===========
// grid 432 = 144 m-tiles x 3 ky-groups; block 256 (4 waves); 80KB dynamic LDS.
// Counted-vmcnt double-buffer: next stage's 10 global_load_lds stay in flight
// across the barrier (vmcnt(10), never 0 in steady state).  LDS 16B-chunk
// index XOR'd with row&3 on BOTH sides (pre-swizzled global source + swizzled
// ds_read) to spread fragment reads over all 8 bank quads.
__global__ __launch_bounds__(256) void conv2_mfma(
    const unsigned short* __restrict__ xh, const unsigned short* __restrict__ xl,
    const unsigned short* __restrict__ wh, const unsigned short* __restrict__ wl,
    float* __restrict__ part)
{
  extern __shared__ char lds[];
  const int t   = threadIdx.x;
  const int blk = blockIdx.x;
  const int mt  = blk % 144;
  const int kg  = blk / 144;
  const int m0  = mt * 64;
  const int lane = t & 63;
  const int w    = t >> 6;
  const int l31 = lane & 31, lhi = lane >> 5;

  // staging addresses (thread t -> LDS slot row=t>>2, chunk=t&3; source chunk
  // is XOR-swizzled so that LDS slot (row,ch) holds global chunk ch^(row&3))
  const int arow = t >> 2;
  const int aoct = (t & 3) ^ (arow & 3);
  const int apix = m0 + arow;
  const int ab  = apix / 36;
  const int asp = apix - ab * 36;
  const int aoy = asp / 6;
  const int aox = asp - aoy * 6;
  const int abase = ((ab * 20 + 2 * aoy) * 20 + 2 * aox) * 256 + aoct * 8;
  const int bofs0 = arow * 256 + aoct * 8;

  f32x16 acc[2][2];
  #pragma unroll
  for (int i = 0; i < 2; i++)
    #pragma unroll
    for (int j = 0; j < 2; j++)
      #pragma unroll
      for (int k = 0; k < 16; k++) acc[i][j][k] = 0.f;

  const int ky0 = kg * 3;

  auto stage = [&](int buf, int ky, int kx, int ci0) {
    char* base = lds + buf * 40960;
    const int axy = (ky * 20 + kx) * 256;
    const int wxy = (ky * 9 + kx) * 65536;
    gload16(xh + abase + axy + ci0, base + t * 16);
    gload16(xl + abase + axy + ci0, base + 4096 + t * 16);
    const unsigned short* wph = wh + wxy + ci0 + bofs0;
    const unsigned short* wpl = wl + wxy + ci0 + bofs0;
    char* bhd = base + 8192  + t * 16;
    char* bld = base + 24576 + t * 16;
    #pragma unroll
    for (int i = 0; i < 4; i++) {
      gload16(wph + i * 16384, bhd + i * 4096);
      gload16(wpl + i * 16384, bld + i * 4096);
    }
  };

  stage(0, ky0, 0, 0);

  int kyn = ky0, kxn = 0, ccn = 0;
  #pragma unroll 1
  for (int s = 0; s < 216; ++s) {
    const int cur = s & 1;
    ccn++;
    if (ccn == 8) { ccn = 0; kxn++; if (kxn == 9) { kxn = 0; kyn++; } }
    if (s < 215) {
      stage(cur ^ 1, kyn, kxn, ccn * 32);
      asm volatile("s_waitcnt vmcnt(10)" ::: "memory");   // stage(s) done, stage(s+1) in flight
    } else {
      asm volatile("s_waitcnt vmcnt(0)" ::: "memory");
    }
    asm volatile("s_barrier" ::: "memory");

    char* base = lds + cur * 40960;
    short8 ah[2][2], al[2][2], bh2[2][2], bl2[2][2];   // [frag][ksub]
    #pragma unroll
    for (int m = 0; m < 2; m++) {
      const int row = m * 32 + l31;
      #pragma unroll
      for (int ks = 0; ks < 2; ks++) {
        const int off = row * 64 + ((((ks << 1) | lhi) ^ (row & 3)) << 4);
        ah[m][ks] = *(const short8*)(base + off);
        al[m][ks] = *(const short8*)(base + 4096 + off);
      }
    }
    #pragma unroll
    for (int n = 0; n < 2; n++) {
      const int row = n * 32 + l31;
      #pragma unroll
      for (int ks = 0; ks < 2; ks++) {
        const int off = (w << 12) + row * 64 + ((((ks << 1) | lhi) ^ (row & 3)) << 4);
        bh2[n][ks] = *(const short8*)(base + 8192  + off);
        bl2[n][ks] = *(const short8*)(base + 24576 + off);
      }
    }
    __builtin_amdgcn_s_setprio(1);
    #pragma unroll
    for (int ks = 0; ks < 2; ks++)
      #pragma unroll
      for (int m = 0; m < 2; m++)
        #pragma unroll
        for (int n = 0; n < 2; n++) {
          acc[m][n] = __builtin_amdgcn_mfma_f32_32x32x16_bf16(ah[m][ks], bh2[n][ks], acc[m][n], 0, 0, 0);
          acc[m][n] = __builtin_amdgcn_mfma_f32_32x32x16_bf16(al[m][ks], bh2[n][ks], acc[m][n], 0, 0, 0);
          acc[m][n] = __builtin_amdgcn_mfma_f32_32x32x16_bf16(ah[m][ks], bl2[n][ks], acc[m][n], 0, 0, 0);
        }
    __builtin_amdgcn_s_setprio(0);
    asm volatile("s_barrier" ::: "memory");
  }

  // epilogue: 32x32 C/D layout: col=lane&31, row=(reg&3)+8*(reg>>2)+4*(lane>>5)
  float* pout = part + kg * 2359296;
  #pragma unroll
  for (int m = 0; m < 2; m++)
    #pragma unroll
    for (int n = 0; n < 2; n++) {
      const int co = (w << 6) + n * 32 + l31;
      #pragma unroll
      for (int reg = 0; reg < 16; reg++) {
        const int pix = m0 + m * 32 + (reg & 3) + ((reg >> 2) << 3) + (lhi << 2);
        const int b  = pix / 36;
        const int sp = pix - b * 36;
        pout[b * 9216 + co * 36 + sp] = acc[m][n][reg];
      }
    }
}

// ======== combine 3 split-K partials + bias, squash(8); emit u_T only =======
__global__ void combine_squash(const float* __restrict__ part,
                               const float* __restrict__ pb,
                               float* __restrict__ uT)
{
  const int id = blockIdx.x * 256 + threadIdx.x;  // 0..294911
  const int b = id / 1152;
  const int r = id % 1152;
  const float* p0 = part + b * 9216 + r * 8;
  float v[8];
  #pragma unroll
  for (int i = 0; i < 8; i++) v[i] = p0[i] + p0[2359296 + i] + p0[4718592 + i];
  #pragma unroll
  for (int i = 0; i < 8; i++) v[i] += pb[(r * 8 + i) / 36];
  float sq = 0.f;
  #pragma unroll
  for (int i = 0; i < 8; i++) sq += v[i] * v[i];
  float scale = sq / ((1.f + sq) * sqrtf(sq));
  #pragma unroll
  for (int i = 0; i < 8; i++) uT[(r * 256 + b) * 8 + i] = v[i] * scale;
}

// ===== s partials: grid 640 = 10 c x 64 r-chunks(18); block 256 (thread=b) ==
// W chunk staged once in LDS (total W traffic 5.9MB/pass); route softmax
// computed inline from bij (global max/sum over the full 1152 column).
__global__ __launch_bounds__(256) void s_pass(
    const float* __restrict__ uT, const float* __restrict__ Wdc,
    const float* __restrict__ bij, float* __restrict__ spart, int uniform)
{
  const int c  = blockIdx.x % 10;
  const int q  = blockIdx.x / 10;          // 0..63
  const int r0 = q * 18;
  const int t  = threadIdx.x;
  __shared__ float wsm[18 * 128];          // 9216 B
  __shared__ float cw[18];
  __shared__ float red[8];

  #pragma unroll
  for (int k = 0; k < 9; k++) {
    int idx = t + k * 256;                 // < 2304
    int r = idx >> 7, i = idx & 127;
    wsm[idx] = Wdc[((r0 + r) * 10 + c) * 128 + i];
  }
  if (uniform) {
    if (t < 18) cw[t] = 1.f / 1152.f;
  } else {
    float bv[5]; float m = -1e30f;
    #pragma unroll
    for (int rr = 0; rr < 5; rr++) {
      int r = t + rr * 256;
      bv[rr] = (r < 1152) ? bij[c * 1152 + r] : -1e30f;
      m = fmaxf(m, bv[rr]);
    }
    #pragma unroll
    for (int off = 32; off; off >>= 1) m = fmaxf(m, __shfl_down(m, off, 64));
    if ((t & 63) == 0) red[t >> 6] = m;
    __syncthreads();
    m = fmaxf(fmaxf(red[0], red[1]), fmaxf(red[2], red[3]));
    float ssum = 0.f;
    #pragma unroll
    for (int rr = 0; rr < 5; rr++)
      ssum += (t + rr * 256 < 1152) ? expf(bv[rr] - m) : 0.f;
    #pragma unroll
    for (int off = 32; off; off >>= 1) ssum += __shfl_down(ssum, off, 64);
    if ((t & 63) == 0) red[4 + (t >> 6)] = ssum;
    __syncthreads();
    float inv = 1.f / (red[4] + red[5] + red[6] + red[7]);
    if (t < 18) cw[t] = expf(bij[c * 1152 + r0 + t] - m) * inv;
  }
  __syncthreads();

  const float4* up = (const float4*)(uT + (r0 * 256 + t) * 8);
  float acc[16];
  #pragma unroll
  for (int o = 0; o < 16; o++) acc[o] = 0.f;
  #pragma unroll 1
  for (int r = 0; r < 18; r++) {
    float4 x0 = up[r * 512], x1 = up[r * 512 + 1];
    float cwr = cw[r];
    const float* wr = &wsm[r * 128];
    #pragma unroll
    for (int o = 0; o < 16; o++) {
      const float4 wa = *(const float4*)(wr + o * 8);
      const float4 wb = *(const float4*)(wr + o * 8 + 4);
      acc[o] += cwr * (wa.x*x0.x + wa.y*x0.y + wa.z*x0.z + wa.w*x0.w
                     + wb.x*x1.x + wb.y*x1.y + wb.z*x1.z + wb.w*x1.w);
    }
  }
  float* op = spart + q * 40960 + (t * 10 + c) * 16;
  #pragma unroll
  for (int o = 0; o < 16; o++) op[o] = acc[o];
}

// ================= sum the 64 r-chunk partials into sbuf ====================
__global__ void reduce_s(const float* __restrict__ spart, float* __restrict__ sbuf)
{
  const int id = blockIdx.x * 256 + threadIdx.x;   // < 40960
  float a = 0.f;
  #pragma unroll 8
  for (int q = 0; q < 64; q++) a += spart[q * 40960 + id];
  sbuf[id] = a;
}

// ======================== v = squash(s) -> vT (non-final iters) =============
__global__ void squash_nf(const float* __restrict__ s, float* __restrict__ vT)
{
  const int id = blockIdx.x * 256 + threadIdx.x;  // b*10+c
  const int b = id / 10, c = id - b * 10;
  const float4* sp = (const float4*)(s + id * 16);
  float4 q0 = sp[0], q1 = sp[1], q2 = sp[2], q3 = sp[3];
  float sq = q0.x*q0.x+q0.y*q0.y+q0.z*q0.z+q0.w*q0.w
           + q1.x*q1.x+q1.y*q1.y+q1.z*q1.z+q1.w*q1.w
           + q2.x*q2.x+q2.y*q2.y+q2.z*q2.z+q2.w*q2.w
           + q3.x*q3.x+q3.y*q3.y+q3.z*q3.z+q3.w*q3.w;
  float scale = sq / ((1.f + sq) * sqrtf(sq));
  float4* vp = (float4*)(vT + (c * 256 + b) * 16);
  vp[0] = make_float4(q0.x*scale, q0.y*scale, q0.z*scale, q0.w*scale);
  vp[1] = make_float4(q1.x*scale, q1.y*scale, q1.z*scale, q1.w*scale);
  vp[2] = make_float4(q2.x*scale, q2.y*scale, q2.z*scale, q2.w*scale);
  vp[3] = make_float4(q3.x*scale, q3.y*scale, q3.z*scale, q3.w*scale);
}

// == a[r,c] = (1/B) sum_{b,o} dot(W[r,c,o],u[b,r]) * v[b,c,o]; bij (+)= a ====
__global__ __launch_bounds__(256) void a_pass(
    const float* __restrict__ uT, const float* __restrict__ W,
    const float* __restrict__ vT, float* __restrict__ bij, int assign)
{
  const int r = blockIdx.x;
  const int t = threadIdx.x;
  __shared__ float wsl[1280];
  __shared__ float lred[4][10];
  for (int i = t; i < 1280; i += 256) wsl[i] = W[r * 1280 + i];
  __syncthreads();
  const float4* up = (const float4*)(uT + (r * 256 + t) * 8);
  float4 ua = up[0], ub = up[1];
  const int lane = t & 63, wid = t >> 6;
  #pragma unroll 1
  for (int c = 0; c < 10; c++) {
    const float* wc = &wsl[c * 128];
    const float4* vp = (const float4*)(vT + (c * 256 + t) * 16);
    float p = 0.f;
    #pragma unroll
    for (int q = 0; q < 4; q++) {
      float4 vq = vp[q];
      p += dot8(wc + (q * 4 + 0) * 8, ua, ub) * vq.x;
      p += dot8(wc + (q * 4 + 1) * 8, ua, ub) * vq.y;
      p += dot8(wc + (q * 4 + 2) * 8, ua, ub) * vq.z;
      p += dot8(wc + (q * 4 + 3) * 8, ua, ub) * vq.w;
    }
    for (int off = 32; off; off >>= 1) p += __shfl_down(p, off, 64);
    if (lane == 0) lred[wid][c] = p;
  }
  __syncthreads();
  if (t < 10) {
    float a = (lred[0][t] + lred[1][t] + lred[2][t] + lred[3][t]) * (1.f / 256.f);
    float o = assign ? 0.f : bij[t * 1152 + r];
    bij[t * 1152 + r] = o + a;
  }
}

// == finalize: squash(final) -> outp; batch softmax; argmax mask; t vector ===
// 1 block x 256 threads (thread = b)
__global__ __launch_bounds__(256) void finalize(
    const float* __restrict__ sbuf, float* __restrict__ outp,
    float* __restrict__ maskedo, float* __restrict__ tbuf)
{
  const int b = threadIdx.x;
  __shared__ float nsm[256][10];
  __shared__ float red[8];
  #pragma unroll 1
  for (int c = 0; c < 10; c++) {
    const float4* sp = (const float4*)(sbuf + (b * 10 + c) * 16);
    float4 q0 = sp[0], q1 = sp[1], q2 = sp[2], q3 = sp[3];
    float sq = q0.x*q0.x+q0.y*q0.y+q0.z*q0.z+q0.w*q0.w
             + q1.x*q1.x+q1.y*q1.y+q1.z*q1.z+q1.w*q1.w
             + q2.x*q2.x+q2.y*q2.y+q2.z*q2.z+q2.w*q2.w
             + q3.x*q3.x+q3.y*q3.y+q3.z*q3.z+q3.w*q3.w;
    float scale = sq / ((1.f + sq) * sqrtf(sq));
    float4* op = (float4*)(outp + (b * 10 + c) * 16);
    op[0] = make_float4(q0.x*scale, q0.y*scale, q0.z*scale, q0.w*scale);
    op[1] = make_float4(q1.x*scale, q1.y*scale, q1.z*scale, q1.w*scale);
    op[2] = make_float4(q2.x*scale, q2.y*scale, q2.z*scale, q2.w*scale);
    op[3] = make_float4(q3.x*scale, q3.y*scale, q3.z*scale, q3.w*scale);
    nsm[b][c] = sq / (1.f + sq);          // = ||squash(s)||
  }
  __syncthreads();
  float sc[10];
  #pragma unroll
  for (int c = 0; c < 10; c++) {
    float x = nsm[b][c];
    float m = x;
    #pragma unroll
    for (int off = 32; off; off >>= 1) m = fmaxf(m, __shfl_down(m, off, 64));
    if ((b & 63) == 0) red[b >> 6] = m;
    __syncthreads();
    m = fmaxf(fmaxf(red[0], red[1]), fmaxf(red[2], red[3]));
    float e = expf(x - m), ss = e;
    #pragma unroll
    for (int off = 32; off; off >>= 1) ss += __shfl_down(ss, off, 64);
    if ((b & 63) == 0) red[4 + (b >> 6)] = ss;
    __syncthreads();
    sc[c] = e / (red[4] + red[5] + red[6] + red[7]);
    __syncthreads();
  }
  int idx = 0; float best = sc[0];
  #pragma unroll
  for (int c = 1; c < 10; c++) if (sc[c] > best) { best = sc[c]; idx = c; }
  #pragma unroll
  for (int c = 0; c < 10; c++) {
    float msk = (c == idx) ? 1.f : 0.f;
    maskedo[b * 10 + c] = msk;
    const float4* op = (const float4*)(outp + (b * 10 + c) * 16);
    float4* tp = (float4*)(tbuf + b * 160 + c * 16);
    #pragma unroll
    for (int qq = 0; qq < 4; qq++) {
      float4 vv = op[qq];
      tp[qq] = make_float4(vv.x * msk, vv.y * msk, vv.z * msk, vv.w * msk);
    }
  }
}

// ==================== small GEMM: C = act(A[M,K] @ B[K,N] + bias) ===========
template <int ACT>
__global__ __launch_bounds__(256) void gemm_act(
    const float* __restrict__ A, const float* __restrict__ B,
    const float* __restrict__ bias, float* __restrict__ C, int M, int N, int K)
{
  __shared__ float As[64][17];
  __shared__ float Bs[16][64];
  const int t = threadIdx.x;
  const int tx = t & 15, ty = t >> 4;
  const int m0 = blockIdx.y * 64, n0 = blockIdx.x * 64;
  float acc[4][4] = {};
  for (int kb = 0; kb < K; kb += 16) {
    {
      int row = t >> 2, c4 = (t & 3) * 4;
      float4 av = *(const float4*)(A + (m0 + row) * K + kb + c4);
      As[row][c4+0]=av.x; As[row][c4+1]=av.y; As[row][c4+2]=av.z; As[row][c4+3]=av.w;
    }
    {
      int row = t >> 4, c4 = (t & 15) * 4;
      float4 bv = make_float4(0.f, 0.f, 0.f, 0.f);
      if (n0 + c4 < N) bv = *(const float4*)(B + (kb + row) * N + n0 + c4);
      Bs[row][c4+0]=bv.x; Bs[row][c4+1]=bv.y; Bs[row][c4+2]=bv.z; Bs[row][c4+3]=bv.w;
    }
    __syncthreads();
    #pragma unroll
    for (int kk = 0; kk < 16; kk++) {
      float a_[4], b_[4];
      #pragma unroll
      for (int i = 0; i < 4; i++) a_[i] = As[ty * 4 + i][kk];
      #pragma unroll
      for (int j = 0; j < 4; j++) b_[j] = Bs[kk][tx * 4 + j];
      #pragma unroll
      for (int i = 0; i < 4; i++)
        for (int j = 0; j < 4; j++)
          acc[i][j] = fmaf(a_[i], b_[j], acc[i][j]);
    }
    __syncthreads();
  }
  #pragma unroll
  for (int i = 0; i < 4; i++) {
    int row = m0 + ty * 4 + i;
    #pragma unroll
    for (int j = 0; j < 4; j++) {
      int col = n0 + tx * 4 + j;
      if (col < N) {
        float val = acc[i][j] + bias[col];
        if (ACT == 0) val = val > 0.f ? val : 0.f;
        else          val = 1.f / (1.f + expf(-val));
        C[row * N + col] = val;
      }
    }
  }
}

// ===========================================================================
extern "C" void kernel_launch(void* const* d_in, const int* in_sizes, int n_in,
                              void* d_out, int out_size, void* d_ws, size_t ws_size,
                              hipStream_t stream)
{
  const float* data = (const float*)d_in[0];
  const float* w1   = (const float*)d_in[1];
  const float* b1   = (const float*)d_in[2];
  const float* pw   = (const float*)d_in[3];
  const float* pb   = (const float*)d_in[4];
  const float* Wdc  = (const float*)d_in[5];
  const float* dw1  = (const float*)d_in[6];
  const float* db1  = (const float*)d_in[7];
  const float* dw2  = (const float*)d_in[8];
  const float* db2  = (const float*)d_in[9];
  const float* dw3  = (const float*)d_in[10];
  const float* db3  = (const float*)d_in[11];

  float* out     = (float*)d_out;
  float* outp    = out;              // [256][10][16][1]
  float* recon   = out + 40960;      // [256][784]
  float* maskedo = out + 241664;     // [256][10]

  char* wsb = (char*)d_ws;
  // big section (conv phase)
  unsigned short* x1h = (unsigned short*)(wsb);               // 52,428,800 B
  unsigned short* x1l = (unsigned short*)(wsb + 52428800);    // 52,428,800
  unsigned short* wbh = (unsigned short*)(wsb + 104857600);   // 10,616,832
  unsigned short* wbl = (unsigned short*)(wsb + 115474432);   // 10,616,832
  float*  part = (float*)(wsb + 126091264);                   // 28,311,552
  // overlay section (x1h region is dead after conv2)
  float* uT   = (float*)(wsb);                                //  9,437,184
  float* vT   = (float*)(wsb + 9437184);                      //    163,840
  float* bij  = (float*)(wsb + 9601024);                      //     46,080
  float* sbuf = (float*)(wsb + 9647104);                      //    163,840
  float* spart= (float*)(wsb + 9810944);                      // 10,485,760
  float* tbuf = (float*)(wsb + 20296704);                     //    163,840
  float* h1   = (float*)(wsb + 20460544);                     //    524,288
  float* h2   = (float*)(wsb + 20984832);                     //  1,048,576

  conv1_kernel<<<1024, 320, 0, stream>>>(data, w1, b1, x1h, x1l);
  wprep<<<256, 256, 0, stream>>>(pw, wbh, wbl);
  conv2_mfma<<<432, 256, 81920, stream>>>(x1h, x1l, wbh, wbl, part);
  combine_squash<<<1152, 256, 0, stream>>>(part, pb, uT);

  // routing iteration 0 (b_ij = 0 -> uniform c); b_ij assigned, not added
  s_pass<<<640, 256, 0, stream>>>(uT, Wdc, bij, spart, 1);
  reduce_s<<<160, 256, 0, stream>>>(spart, sbuf);
  squash_nf<<<10, 256, 0, stream>>>(sbuf, vT);
  a_pass<<<1152, 256, 0, stream>>>(uT, Wdc, vT, bij, 1);
  // iteration 1
  s_pass<<<640, 256, 0, stream>>>(uT, Wdc, bij, spart, 0);
  reduce_s<<<160, 256, 0, stream>>>(spart, sbuf);
  squash_nf<<<10, 256, 0, stream>>>(sbuf, vT);
  a_pass<<<1152, 256, 0, stream>>>(uT, Wdc, vT, bij, 0);
  // iteration 2 (final) + fused decoder head
  s_pass<<<640, 256, 0, stream>>>(uT, Wdc, bij, spart, 0);
  reduce_s<<<160, 256, 0, stream>>>(spart, sbuf);
  finalize<<<1, 256, 0, stream>>>(sbuf, outp, maskedo, tbuf);

  gemm_act<0><<<dim3(8, 4),  256, 0, stream>>>(tbuf, dw1, db1, h1,    256, 512,  160);
  gemm_act<0><<<dim3(16, 4), 256, 0, stream>>>(h1,   dw2, db2, h2,    256, 1024, 512);
  gemm_act<1><<<dim3(13, 4), 256, 0, stream>>>(h2,   dw3, db3, recon, 256, 784,  1024);
}

// Round 5
// 779.784 us; speedup vs baseline: 4.7193x; 1.1000x over previous
//
#include <hip/hip_runtime.h>
#include <math.h>

// ---------------------------------------------------------------------------
// CapsNet forward.  conv1 fp32 -> bf16(hi,lo) channel-last -> conv2 as
// implicit-GEMM MFMA 16x16x32 (bf16x2 compensated, fp32 accum), 128x256 block
// tile / 64x128 wave tile, bank-swizzled LDS (s = g ^ (row&7)), counted-vmcnt
// double buffer -> squash -> routing -> fused finalize -> decoder MLP (fp32).
// ---------------------------------------------------------------------------

typedef __attribute__((ext_vector_type(8))) short short8;
typedef __attribute__((ext_vector_type(4))) float f32x4;

__device__ __forceinline__ unsigned short f2bf(float x) {
  unsigned int u = __float_as_uint(x);
  unsigned int r = (u + 0x7fffu + ((u >> 16) & 1u)) >> 16;
  return (unsigned short)r;
}
__device__ __forceinline__ float bf2f(unsigned short h) {
  return __uint_as_float(((unsigned int)h) << 16);
}
__device__ __forceinline__ void gload16(const void* g, void* l) {
  __builtin_amdgcn_global_load_lds(
      (const __attribute__((address_space(1))) unsigned int*)g,
      (__attribute__((address_space(3))) unsigned int*)l, 16, 0, 0);
}
__device__ __forceinline__ float dot8(const float* w, float4 a, float4 b) {
  return w[0]*a.x + w[1]*a.y + w[2]*a.z + w[3]*a.w +
         w[4]*b.x + w[5]*b.y + w[6]*b.z + w[7]*b.w;
}

// ======================= conv1: [256,1,28,28] -> bf16x2 CL [256,20,20,256] ==
// grid 1024 = 256 b x 4 co-groups(64 co); block 320 = 16 co-quads x 20 oy
__global__ __launch_bounds__(320) void conv1_kernel(
    const float* __restrict__ data, const float* __restrict__ w1,
    const float* __restrict__ b1, unsigned short* __restrict__ xh,
    unsigned short* __restrict__ xl)
{
  const int bid = blockIdx.x;
  const int b   = bid >> 2;
  const int cog = bid & 3;
  __shared__ float img[784];
  __shared__ float wsm[81][64];
  const int t = threadIdx.x;
  for (int i = t; i < 784; i += 320) img[i] = data[b * 784 + i];
  for (int i = t; i < 64 * 81; i += 320) {
    int col = i / 81, k = i % 81;
    wsm[k][col] = w1[(cog * 64 + col) * 81 + k];
  }
  __syncthreads();
  const int cg = t & 15;
  const int oy = t >> 4;           // 0..19
  const int co0 = cog * 64 + cg * 4;
  float acc[4][20];
  #pragma unroll
  for (int i = 0; i < 4; i++) {
    float bv = b1[co0 + i];
    #pragma unroll
    for (int j = 0; j < 20; j++) acc[i][j] = bv;
  }
  for (int ky = 0; ky < 9; ky++) {
    float xr[28];
    const float4* rp = reinterpret_cast<const float4*>(&img[(oy + ky) * 28]);
    #pragma unroll
    for (int q = 0; q < 7; q++) {
      float4 v4 = rp[q];
      xr[q*4+0] = v4.x; xr[q*4+1] = v4.y; xr[q*4+2] = v4.z; xr[q*4+3] = v4.w;
    }
    #pragma unroll
    for (int kx = 0; kx < 9; kx++) {
      float4 wv = *reinterpret_cast<const float4*>(&wsm[ky * 9 + kx][cg * 4]);
      #pragma unroll
      for (int ox = 0; ox < 20; ox++) {
        float xv = xr[ox + kx];
        acc[0][ox] = fmaf(xv, wv.x, acc[0][ox]);
        acc[1][ox] = fmaf(xv, wv.y, acc[1][ox]);
        acc[2][ox] = fmaf(xv, wv.z, acc[2][ox]);
        acc[3][ox] = fmaf(xv, wv.w, acc[3][ox]);
      }
    }
  }
  #pragma unroll
  for (int ox = 0; ox < 20; ox++) {
    ushort4 hv, lv;
    float v0 = fmaxf(acc[0][ox], 0.f), v1 = fmaxf(acc[1][ox], 0.f);
    float v2 = fmaxf(acc[2][ox], 0.f), v3 = fmaxf(acc[3][ox], 0.f);
    hv.x = f2bf(v0); lv.x = f2bf(v0 - bf2f(hv.x));
    hv.y = f2bf(v1); lv.y = f2bf(v1 - bf2f(hv.y));
    hv.z = f2bf(v2); lv.z = f2bf(v2 - bf2f(hv.z));
    hv.w = f2bf(v3); lv.w = f2bf(v3 - bf2f(hv.w));
    const int pix = (b * 20 + oy) * 20 + ox;
    *(ushort4*)(xh + pix * 256 + co0) = hv;
    *(ushort4*)(xl + pix * 256 + co0) = lv;
  }
}

// ===== conv2 weight prep: pw[co][ci][81] fp32 -> w[k][co][ci] bf16 hi/lo ====
__global__ void wprep(const float* __restrict__ pw, unsigned short* __restrict__ wh,
                      unsigned short* __restrict__ wl)
{
  const int co = blockIdx.x;
  const int t  = threadIdx.x;
  __shared__ float slab[20736];   // [ci][81] for this co
  for (int i = t; i < 20736; i += 256) slab[i] = pw[co * 20736 + i];
  __syncthreads();
  for (int k = 0; k < 81; k++) {
    float x = slab[t * 81 + k];
    unsigned short h = f2bf(x);
    wh[(k * 256 + co) * 256 + t] = h;
    wl[(k * 256 + co) * 256 + t] = f2bf(x - bf2f(h));
  }
}

// ===== conv2 MFMA: block 128pix x 256co, wave 64x128, 3-way ky split-K ======
// grid 216 = 72 m-tiles x 3 ky-groups; 256 thr (4 waves); 96KB dynamic LDS.
// LDS swizzle: 16B granule g=(row*4+ch) stored at slot s = g ^ (row&7) —
// every 8-lane subgroup of a fragment read hits 8 distinct bank quads.
// Staging inverts the XOR on the per-lane GLOBAL address (LDS dest linear).
__global__ __launch_bounds__(256, 1) void conv2_mfma(
    const unsigned short* __restrict__ xh, const unsigned short* __restrict__ xl,
    const unsigned short* __restrict__ wh, const unsigned short* __restrict__ wl,
    float* __restrict__ part)
{
  extern __shared__ char lds[];
  const int t   = threadIdx.x;
  const int blk = blockIdx.x;
  const int mt  = blk % 72;
  const int kg  = blk / 72;
  const int m0  = mt * 128;
  const int lane = t & 63;
  const int w    = t >> 6;
  const int l15  = lane & 15, l4 = lane >> 4;
  const int mh   = w >> 1, nh = w & 1;      // wave tile: rows [mh*64,+64), cols [nh*128,+128)
  const int swz  = l15 & 7;

  // ---- staging source decode: slot t holds granule g = inv(t) --------------
  const int ib2 = ((t >> 2) ^ (t >> 4)) & 1;
  const int ib1 = ((t >> 1) ^ (t >> 3)) & 1;
  const int ib0 = (t ^ (t >> 2) ^ (t >> 4)) & 1;
  const int g   = (t & ~7) | (ib2 << 2) | (ib1 << 1) | ib0;
  const int ar  = g >> 2;                   // source row 0..63 (+64 for 2nd slot)
  const int ach = g & 3;                    // source 16B chunk within row

  auto pixbase = [&](int pix) {
    int ab = pix / 36; int sp = pix - ab * 36;
    int oy = sp / 6;   int ox = sp - oy * 6;
    return ((ab * 20 + 2 * oy) * 20 + 2 * ox) * 256;
  };
  const int abase0 = pixbase(m0 + ar) + ach * 8;
  const int abase1 = pixbase(m0 + ar + 64) + ach * 8;
  const int bofs   = ar * 256 + ach * 8;    // co=ar (+64i), chunk ach

  f32x4 acc[4][8];
  #pragma unroll
  for (int i = 0; i < 4; i++)
    #pragma unroll
    for (int j = 0; j < 8; j++) acc[i][j] = (f32x4){0.f, 0.f, 0.f, 0.f};

  const int ky0 = kg * 3;

  auto stage = [&](int buf, int ky, int kx, int ci0) {
    char* base = lds + buf * 49152;
    const int axy = (ky * 20 + kx) * 256 + ci0;
    const int wxy = (ky * 9 + kx) * 65536 + ci0 + bofs;
    gload16(xh + abase0 + axy, base + t * 16);            // A_hi rows 0-63
    gload16(xh + abase1 + axy, base + 4096  + t * 16);    // A_hi rows 64-127
    gload16(xl + abase0 + axy, base + 8192  + t * 16);    // A_lo
    gload16(xl + abase1 + axy, base + 12288 + t * 16);
    const unsigned short* wph = wh + wxy;
    const unsigned short* wpl = wl + wxy;
    char* bh = base + 16384 + t * 16;
    char* bl = base + 32768 + t * 16;
    #pragma unroll
    for (int i = 0; i < 4; i++) {                         // co = ar + 64*i
      gload16(wph + i * 16384, bh + i * 4096);
      gload16(wpl + i * 16384, bl + i * 4096);
    }
  };

  stage(0, ky0, 0, 0);

  int kyn = ky0, kxn = 0, ccn = 0;
  #pragma unroll 1
  for (int s = 0; s < 216; ++s) {
    const int cur = s & 1;
    ccn++;
    if (ccn == 8) { ccn = 0; kxn++; if (kxn == 9) { kxn = 0; kyn++; } }
    if (s < 215) {
      stage(cur ^ 1, kyn, kxn, ccn * 32);
      asm volatile("s_waitcnt vmcnt(12)" ::: "memory");   // stage(s) done; s+1 in flight
    } else {
      asm volatile("s_waitcnt vmcnt(0)" ::: "memory");
    }
    asm volatile("s_barrier" ::: "memory");

    char* base = lds + cur * 49152;
    short8 a_h[4], a_l[4];
    #pragma unroll
    for (int mf = 0; mf < 4; mf++) {
      const int row = mh * 64 + mf * 16 + l15;
      const int off = ((((row << 2) | l4) ^ swz) << 4);
      a_h[mf] = *(const short8*)(base + off);
      a_l[mf] = *(const short8*)(base + 8192 + off);
    }
    #pragma unroll
    for (int half = 0; half < 2; half++) {
      short8 b_h[4], b_l[4];
      #pragma unroll
      for (int j = 0; j < 4; j++) {
        const int row = nh * 128 + (half * 4 + j) * 16 + l15;
        const int off = ((((row << 2) | l4) ^ swz) << 4);
        b_h[j] = *(const short8*)(base + 16384 + off);
        b_l[j] = *(const short8*)(base + 32768 + off);
      }
      __builtin_amdgcn_s_setprio(1);
      #pragma unroll
      for (int j = 0; j < 4; j++)
        #pragma unroll
        for (int mf = 0; mf < 4; mf++) {
          f32x4 a = acc[mf][half * 4 + j];
          a = __builtin_amdgcn_mfma_f32_16x16x32_bf16(a_h[mf], b_h[j], a, 0, 0, 0);
          a = __builtin_amdgcn_mfma_f32_16x16x32_bf16(a_l[mf], b_h[j], a, 0, 0, 0);
          a = __builtin_amdgcn_mfma_f32_16x16x32_bf16(a_h[mf], b_l[j], a, 0, 0, 0);
          acc[mf][half * 4 + j] = a;
        }
      __builtin_amdgcn_s_setprio(0);
    }
    asm volatile("s_barrier" ::: "memory");
  }

  // epilogue: C[pix][co]; 16x16 C/D: col=lane&15, row=(lane>>4)*4+reg
  float* pout = part + kg * 2359296;
  #pragma unroll
  for (int mf = 0; mf < 4; mf++)
    #pragma unroll
    for (int nf = 0; nf < 8; nf++) {
      const int co = nh * 128 + nf * 16 + l15;
      #pragma unroll
      for (int reg = 0; reg < 4; reg++) {
        const int pix = m0 + mh * 64 + mf * 16 + l4 * 4 + reg;
        const int b  = pix / 36;
        const int sp = pix - b * 36;
        pout[b * 9216 + co * 36 + sp] = acc[mf][nf][reg];
      }
    }
}

// ======== combine 3 split-K partials + bias, squash(8); emit u_T only =======
__global__ void combine_squash(const float* __restrict__ part,
                               const float* __restrict__ pb,
                               float* __restrict__ uT)
{
  const int id = blockIdx.x * 256 + threadIdx.x;  // 0..294911
  const int b = id / 1152;
  const int r = id % 1152;
  const float* p0 = part + b * 9216 + r * 8;
  float v[8];
  #pragma unroll
  for (int i = 0; i < 8; i++) v[i] = p0[i] + p0[2359296 + i] + p0[4718592 + i];
  #pragma unroll
  for (int i = 0; i < 8; i++) v[i] += pb[(r * 8 + i) / 36];
  float sq = 0.f;
  #pragma unroll
  for (int i = 0; i < 8; i++) sq += v[i] * v[i];
  float scale = sq / ((1.f + sq) * sqrtf(sq));
  #pragma unroll
  for (int i = 0; i < 8; i++) uT[(r * 256 + b) * 8 + i] = v[i] * scale;
}

// ===== s partials: grid 640 = 10 c x 64 r-chunks(18); block 256 (thread=b) ==
__global__ __launch_bounds__(256) void s_pass(
    const float* __restrict__ uT, const float* __restrict__ Wdc,
    const float* __restrict__ bij, float* __restrict__ spart, int uniform)
{
  const int c  = blockIdx.x % 10;
  const int q  = blockIdx.x / 10;          // 0..63
  const int r0 = q * 18;
  const int t  = threadIdx.x;
  __shared__ float wsm[18 * 128];          // 9216 B
  __shared__ float cw[18];
  __shared__ float red[8];

  #pragma unroll
  for (int k = 0; k < 9; k++) {
    int idx = t + k * 256;                 // < 2304
    int r = idx >> 7, i = idx & 127;
    wsm[idx] = Wdc[((r0 + r) * 10 + c) * 128 + i];
  }
  if (uniform) {
    if (t < 18) cw[t] = 1.f / 1152.f;
  } else {
    float bv[5]; float m = -1e30f;
    #pragma unroll
    for (int rr = 0; rr < 5; rr++) {
      int r = t + rr * 256;
      bv[rr] = (r < 1152) ? bij[c * 1152 + r] : -1e30f;
      m = fmaxf(m, bv[rr]);
    }
    #pragma unroll
    for (int off = 32; off; off >>= 1) m = fmaxf(m, __shfl_down(m, off, 64));
    if ((t & 63) == 0) red[t >> 6] = m;
    __syncthreads();
    m = fmaxf(fmaxf(red[0], red[1]), fmaxf(red[2], red[3]));
    float ssum = 0.f;
    #pragma unroll
    for (int rr = 0; rr < 5; rr++)
      ssum += (t + rr * 256 < 1152) ? expf(bv[rr] - m) : 0.f;
    #pragma unroll
    for (int off = 32; off; off >>= 1) ssum += __shfl_down(ssum, off, 64);
    if ((t & 63) == 0) red[4 + (t >> 6)] = ssum;
    __syncthreads();
    float inv = 1.f / (red[4] + red[5] + red[6] + red[7]);
    if (t < 18) cw[t] = expf(bij[c * 1152 + r0 + t] - m) * inv;
  }
  __syncthreads();

  const float4* up = (const float4*)(uT + (r0 * 256 + t) * 8);
  float acc[16];
  #pragma unroll
  for (int o = 0; o < 16; o++) acc[o] = 0.f;
  #pragma unroll 1
  for (int r = 0; r < 18; r++) {
    float4 x0 = up[r * 512], x1 = up[r * 512 + 1];
    float cwr = cw[r];
    const float* wr = &wsm[r * 128];
    #pragma unroll
    for (int o = 0; o < 16; o++) {
      const float4 wa = *(const float4*)(wr + o * 8);
      const float4 wb = *(const float4*)(wr + o * 8 + 4);
      acc[o] += cwr * (wa.x*x0.x + wa.y*x0.y + wa.z*x0.z + wa.w*x0.w
                     + wb.x*x1.x + wb.y*x1.y + wb.z*x1.z + wb.w*x1.w);
    }
  }
  float* op = spart + q * 40960 + (t * 10 + c) * 16;
  #pragma unroll
  for (int o = 0; o < 16; o++) op[o] = acc[o];
}

// ================= sum the 64 r-chunk partials into sbuf ====================
__global__ void reduce_s(const float* __restrict__ spart, float* __restrict__ sbuf)
{
  const int id = blockIdx.x * 256 + threadIdx.x;   // < 40960
  float a = 0.f;
  #pragma unroll 8
  for (int q = 0; q < 64; q++) a += spart[q * 40960 + id];
  sbuf[id] = a;
}

// ======================== v = squash(s) -> vT (non-final iters) =============
__global__ void squash_nf(const float* __restrict__ s, float* __restrict__ vT)
{
  const int id = blockIdx.x * 256 + threadIdx.x;  // b*10+c
  const int b = id / 10, c = id - b * 10;
  const float4* sp = (const float4*)(s + id * 16);
  float4 q0 = sp[0], q1 = sp[1], q2 = sp[2], q3 = sp[3];
  float sq = q0.x*q0.x+q0.y*q0.y+q0.z*q0.z+q0.w*q0.w
           + q1.x*q1.x+q1.y*q1.y+q1.z*q1.z+q1.w*q1.w
           + q2.x*q2.x+q2.y*q2.y+q2.z*q2.z+q2.w*q2.w
           + q3.x*q3.x+q3.y*q3.y+q3.z*q3.z+q3.w*q3.w;
  float scale = sq / ((1.f + sq) * sqrtf(sq));
  float4* vp = (float4*)(vT + (c * 256 + b) * 16);
  vp[0] = make_float4(q0.x*scale, q0.y*scale, q0.z*scale, q0.w*scale);
  vp[1] = make_float4(q1.x*scale, q1.y*scale, q1.z*scale, q1.w*scale);
  vp[2] = make_float4(q2.x*scale, q2.y*scale, q2.z*scale, q2.w*scale);
  vp[3] = make_float4(q3.x*scale, q3.y*scale, q3.z*scale, q3.w*scale);
}

// == a[r,c] = (1/B) sum_{b,o} dot(W[r,c,o],u[b,r]) * v[b,c,o]; bij (+)= a ====
// grid 1152 (r); block 256 (thread = b).  Class loop NOT unrolled (VGPR).
__global__ __launch_bounds__(256) void a_pass(
    const float* __restrict__ uT, const float* __restrict__ W,
    const float* __restrict__ vT, float* __restrict__ bij, int assign)
{
  const int r = blockIdx.x;
  const int t = threadIdx.x;
  __shared__ float wsl[1280];
  __shared__ float lred[4][10];
  for (int i = t; i < 1280; i += 256) wsl[i] = W[r * 1280 + i];
  __syncthreads();
  const float4* up = (const float4*)(uT + (r * 256 + t) * 8);
  float4 ua = up[0], ub = up[1];
  const int lane = t & 63, wid = t >> 6;
  #pragma unroll 1
  for (int c = 0; c < 10; c++) {
    const float* wc = &wsl[c * 128];
    const float4* vp = (const float4*)(vT + (c * 256 + t) * 16);
    float p = 0.f;
    #pragma unroll
    for (int q = 0; q < 4; q++) {
      float4 vq = vp[q];
      p += dot8(wc + (q * 4 + 0) * 8, ua, ub) * vq.x;
      p += dot8(wc + (q * 4 + 1) * 8, ua, ub) * vq.y;
      p += dot8(wc + (q * 4 + 2) * 8, ua, ub) * vq.z;
      p += dot8(wc + (q * 4 + 3) * 8, ua, ub) * vq.w;
    }
    for (int off = 32; off; off >>= 1) p += __shfl_down(p, off, 64);
    if (lane == 0) lred[wid][c] = p;
  }
  __syncthreads();
  if (t < 10) {
    float a = (lred[0][t] + lred[1][t] + lred[2][t] + lred[3][t]) * (1.f / 256.f);
    float o = assign ? 0.f : bij[t * 1152 + r];
    bij[t * 1152 + r] = o + a;
  }
}

// == finalize: squash(final) -> outp; batch softmax; argmax mask; t vector ===
__global__ __launch_bounds__(256) void finalize(
    const float* __restrict__ sbuf, float* __restrict__ outp,
    float* __restrict__ maskedo, float* __restrict__ tbuf)
{
  const int b = threadIdx.x;
  __shared__ float nsm[256][10];
  __shared__ float red[8];
  #pragma unroll 1
  for (int c = 0; c < 10; c++) {
    const float4* sp = (const float4*)(sbuf + (b * 10 + c) * 16);
    float4 q0 = sp[0], q1 = sp[1], q2 = sp[2], q3 = sp[3];
    float sq = q0.x*q0.x+q0.y*q0.y+q0.z*q0.z+q0.w*q0.w
             + q1.x*q1.x+q1.y*q1.y+q1.z*q1.z+q1.w*q1.w
             + q2.x*q2.x+q2.y*q2.y+q2.z*q2.z+q2.w*q2.w
             + q3.x*q3.x+q3.y*q3.y+q3.z*q3.z+q3.w*q3.w;
    float scale = sq / ((1.f + sq) * sqrtf(sq));
    float4* op = (float4*)(outp + (b * 10 + c) * 16);
    op[0] = make_float4(q0.x*scale, q0.y*scale, q0.z*scale, q0.w*scale);
    op[1] = make_float4(q1.x*scale, q1.y*scale, q1.z*scale, q1.w*scale);
    op[2] = make_float4(q2.x*scale, q2.y*scale, q2.z*scale, q2.w*scale);
    op[3] = make_float4(q3.x*scale, q3.y*scale, q3.z*scale, q3.w*scale);
    nsm[b][c] = sq / (1.f + sq);          // = ||squash(s)||
  }
  __syncthreads();
  float sc[10];
  #pragma unroll
  for (int c = 0; c < 10; c++) {
    float x = nsm[b][c];
    float m = x;
    #pragma unroll
    for (int off = 32; off; off >>= 1) m = fmaxf(m, __shfl_down(m, off, 64));
    if ((b & 63) == 0) red[b >> 6] = m;
    __syncthreads();
    m = fmaxf(fmaxf(red[0], red[1]), fmaxf(red[2], red[3]));
    float e = expf(x - m), ss = e;
    #pragma unroll
    for (int off = 32; off; off >>= 1) ss += __shfl_down(ss, off, 64);
    if ((b & 63) == 0) red[4 + (b >> 6)] = ss;
    __syncthreads();
    sc[c] = e / (red[4] + red[5] + red[6] + red[7]);
    __syncthreads();
  }
  int idx = 0; float best = sc[0];
  #pragma unroll
  for (int c = 1; c < 10; c++) if (sc[c] > best) { best = sc[c]; idx = c; }
  #pragma unroll
  for (int c = 0; c < 10; c++) {
    float msk = (c == idx) ? 1.f : 0.f;
    maskedo[b * 10 + c] = msk;
    const float4* op = (const float4*)(outp + (b * 10 + c) * 16);
    float4* tp = (float4*)(tbuf + b * 160 + c * 16);
    #pragma unroll
    for (int qq = 0; qq < 4; qq++) {
      float4 vv = op[qq];
      tp[qq] = make_float4(vv.x * msk, vv.y * msk, vv.z * msk, vv.w * msk);
    }
  }
}

// ==================== small GEMM: C = act(A[M,K] @ B[K,N] + bias) ===========
template <int ACT>
__global__ __launch_bounds__(256) void gemm_act(
    const float* __restrict__ A, const float* __restrict__ B,
    const float* __restrict__ bias, float* __restrict__ C, int M, int N, int K)
{
  __shared__ float As[64][17];
  __shared__ float Bs[16][64];
  const int t = threadIdx.x;
  const int tx = t & 15, ty = t >> 4;
  const int m0 = blockIdx.y * 64, n0 = blockIdx.x * 64;
  float acc[4][4] = {};
  for (int kb = 0; kb < K; kb += 16) {
    {
      int row = t >> 2, c4 = (t & 3) * 4;
      float4 av = *(const float4*)(A + (m0 + row) * K + kb + c4);
      As[row][c4+0]=av.x; As[row][c4+1]=av.y; As[row][c4+2]=av.z; As[row][c4+3]=av.w;
    }
    {
      int row = t >> 4, c4 = (t & 15) * 4;
      float4 bv = make_float4(0.f, 0.f, 0.f, 0.f);
      if (n0 + c4 < N) bv = *(const float4*)(B + (kb + row) * N + n0 + c4);
      Bs[row][c4+0]=bv.x; Bs[row][c4+1]=bv.y; Bs[row][c4+2]=bv.z; Bs[row][c4+3]=bv.w;
    }
    __syncthreads();
    #pragma unroll
    for (int kk = 0; kk < 16; kk++) {
      float a_[4], b_[4];
      #pragma unroll
      for (int i = 0; i < 4; i++) a_[i] = As[ty * 4 + i][kk];
      #pragma unroll
      for (int j = 0; j < 4; j++) b_[j] = Bs[kk][tx * 4 + j];
      #pragma unroll
      for (int i = 0; i < 4; i++)
        for (int j = 0; j < 4; j++)
          acc[i][j] = fmaf(a_[i], b_[j], acc[i][j]);
    }
    __syncthreads();
  }
  #pragma unroll
  for (int i = 0; i < 4; i++) {
    int row = m0 + ty * 4 + i;
    #pragma unroll
    for (int j = 0; j < 4; j++) {
      int col = n0 + tx * 4 + j;
      if (col < N) {
        float val = acc[i][j] + bias[col];
        if (ACT == 0) val = val > 0.f ? val : 0.f;
        else          val = 1.f / (1.f + expf(-val));
        C[row * N + col] = val;
      }
    }
  }
}

// ===========================================================================
extern "C" void kernel_launch(void* const* d_in, const int* in_sizes, int n_in,
                              void* d_out, int out_size, void* d_ws, size_t ws_size,
                              hipStream_t stream)
{
  const float* data = (const float*)d_in[0];
  const float* w1   = (const float*)d_in[1];
  const float* b1   = (const float*)d_in[2];
  const float* pw   = (const float*)d_in[3];
  const float* pb   = (const float*)d_in[4];
  const float* Wdc  = (const float*)d_in[5];
  const float* dw1  = (const float*)d_in[6];
  const float* db1  = (const float*)d_in[7];
  const float* dw2  = (const float*)d_in[8];
  const float* db2  = (const float*)d_in[9];
  const float* dw3  = (const float*)d_in[10];
  const float* db3  = (const float*)d_in[11];

  float* out     = (float*)d_out;
  float* outp    = out;              // [256][10][16][1]
  float* recon   = out + 40960;      // [256][784]
  float* maskedo = out + 241664;     // [256][10]

  char* wsb = (char*)d_ws;
  // big section (conv phase)
  unsigned short* x1h = (unsigned short*)(wsb);               // 52,428,800 B
  unsigned short* x1l = (unsigned short*)(wsb + 52428800);    // 52,428,800
  unsigned short* wbh = (unsigned short*)(wsb + 104857600);   // 10,616,832
  unsigned short* wbl = (unsigned short*)(wsb + 115474432);   // 10,616,832
  float*  part = (float*)(wsb + 126091264);                   // 28,311,552
  // overlay section (x1h region is dead after conv2)
  float* uT   = (float*)(wsb);                                //  9,437,184
  float* vT   = (float*)(wsb + 9437184);                      //    163,840
  float* bij  = (float*)(wsb + 9601024);                      //     46,080
  float* sbuf = (float*)(wsb + 9647104);                      //    163,840
  float* spart= (float*)(wsb + 9810944);                      // 10,485,760
  float* tbuf = (float*)(wsb + 20296704);                     //    163,840
  float* h1   = (float*)(wsb + 20460544);                     //    524,288
  float* h2   = (float*)(wsb + 20984832);                     //  1,048,576

  conv1_kernel<<<1024, 320, 0, stream>>>(data, w1, b1, x1h, x1l);
  wprep<<<256, 256, 0, stream>>>(pw, wbh, wbl);
  conv2_mfma<<<216, 256, 98304, stream>>>(x1h, x1l, wbh, wbl, part);
  combine_squash<<<1152, 256, 0, stream>>>(part, pb, uT);

  // routing iteration 0 (b_ij = 0 -> uniform c); b_ij assigned, not added
  s_pass<<<640, 256, 0, stream>>>(uT, Wdc, bij, spart, 1);
  reduce_s<<<160, 256, 0, stream>>>(spart, sbuf);
  squash_nf<<<10, 256, 0, stream>>>(sbuf, vT);
  a_pass<<<1152, 256, 0, stream>>>(uT, Wdc, vT, bij, 1);
  // iteration 1
  s_pass<<<640, 256, 0, stream>>>(uT, Wdc, bij, spart, 0);
  reduce_s<<<160, 256, 0, stream>>>(spart, sbuf);
  squash_nf<<<10, 256, 0, stream>>>(sbuf, vT);
  a_pass<<<1152, 256, 0, stream>>>(uT, Wdc, vT, bij, 0);
  // iteration 2 (final) + fused decoder head
  s_pass<<<640, 256, 0, stream>>>(uT, Wdc, bij, spart, 0);
  reduce_s<<<160, 256, 0, stream>>>(spart, sbuf);
  finalize<<<1, 256, 0, stream>>>(sbuf, outp, maskedo, tbuf);

  gemm_act<0><<<dim3(8, 4),  256, 0, stream>>>(tbuf, dw1, db1, h1,    256, 512,  160);
  gemm_act<0><<<dim3(16, 4), 256, 0, stream>>>(h1,   dw2, db2, h2,    256, 1024, 512);
  gemm_act<1><<<dim3(13, 4), 256, 0, stream>>>(h2,   dw3, db3, recon, 256, 784,  1024);
}

// Round 6
// 692.886 us; speedup vs baseline: 5.3112x; 1.1254x over previous
//
#include <hip/hip_runtime.h>
#include <math.h>

// ---------------------------------------------------------------------------
// CapsNet forward.  conv1 fp32 -> bf16(hi,lo) channel-last -> conv2 as
// implicit-GEMM MFMA 16x16x32 (bf16x2 compensated, fp32 accum): A-only LDS
// (triple-buffered 24KB, swizzled), B streamed L2->registers (each co column
// consumed by exactly one wave -> LDS staging of B saves nothing), counted
// vmcnt, 1 barrier/K-step -> squash -> routing -> finalize -> decoder MLP.
// ---------------------------------------------------------------------------

typedef __attribute__((ext_vector_type(8))) short short8;
typedef __attribute__((ext_vector_type(4))) float f32x4;

__device__ __forceinline__ unsigned short f2bf(float x) {
  unsigned int u = __float_as_uint(x);
  unsigned int r = (u + 0x7fffu + ((u >> 16) & 1u)) >> 16;
  return (unsigned short)r;
}
__device__ __forceinline__ float bf2f(unsigned short h) {
  return __uint_as_float(((unsigned int)h) << 16);
}
__device__ __forceinline__ void gload16(const void* g, void* l) {
  __builtin_amdgcn_global_load_lds(
      (const __attribute__((address_space(1))) unsigned int*)g,
      (__attribute__((address_space(3))) unsigned int*)l, 16, 0, 0);
}
__device__ __forceinline__ float dot8(const float* w, float4 a, float4 b) {
  return w[0]*a.x + w[1]*a.y + w[2]*a.z + w[3]*a.w +
         w[4]*b.x + w[5]*b.y + w[6]*b.z + w[7]*b.w;
}

// ======================= conv1: [256,1,28,28] -> bf16x2 CL [256,20,20,256] ==
__global__ __launch_bounds__(320) void conv1_kernel(
    const float* __restrict__ data, const float* __restrict__ w1,
    const float* __restrict__ b1, unsigned short* __restrict__ xh,
    unsigned short* __restrict__ xl)
{
  const int bid = blockIdx.x;
  const int b   = bid >> 2;
  const int cog = bid & 3;
  __shared__ float img[784];
  __shared__ float wsm[81][64];
  const int t = threadIdx.x;
  for (int i = t; i < 784; i += 320) img[i] = data[b * 784 + i];
  for (int i = t; i < 64 * 81; i += 320) {
    int col = i / 81, k = i % 81;
    wsm[k][col] = w1[(cog * 64 + col) * 81 + k];
  }
  __syncthreads();
  const int cg = t & 15;
  const int oy = t >> 4;           // 0..19
  const int co0 = cog * 64 + cg * 4;
  float acc[4][20];
  #pragma unroll
  for (int i = 0; i < 4; i++) {
    float bv = b1[co0 + i];
    #pragma unroll
    for (int j = 0; j < 20; j++) acc[i][j] = bv;
  }
  for (int ky = 0; ky < 9; ky++) {
    float xr[28];
    const float4* rp = reinterpret_cast<const float4*>(&img[(oy + ky) * 28]);
    #pragma unroll
    for (int q = 0; q < 7; q++) {
      float4 v4 = rp[q];
      xr[q*4+0] = v4.x; xr[q*4+1] = v4.y; xr[q*4+2] = v4.z; xr[q*4+3] = v4.w;
    }
    #pragma unroll
    for (int kx = 0; kx < 9; kx++) {
      float4 wv = *reinterpret_cast<const float4*>(&wsm[ky * 9 + kx][cg * 4]);
      #pragma unroll
      for (int ox = 0; ox < 20; ox++) {
        float xv = xr[ox + kx];
        acc[0][ox] = fmaf(xv, wv.x, acc[0][ox]);
        acc[1][ox] = fmaf(xv, wv.y, acc[1][ox]);
        acc[2][ox] = fmaf(xv, wv.z, acc[2][ox]);
        acc[3][ox] = fmaf(xv, wv.w, acc[3][ox]);
      }
    }
  }
  #pragma unroll
  for (int ox = 0; ox < 20; ox++) {
    ushort4 hv, lv;
    float v0 = fmaxf(acc[0][ox], 0.f), v1 = fmaxf(acc[1][ox], 0.f);
    float v2 = fmaxf(acc[2][ox], 0.f), v3 = fmaxf(acc[3][ox], 0.f);
    hv.x = f2bf(v0); lv.x = f2bf(v0 - bf2f(hv.x));
    hv.y = f2bf(v1); lv.y = f2bf(v1 - bf2f(hv.y));
    hv.z = f2bf(v2); lv.z = f2bf(v2 - bf2f(hv.z));
    hv.w = f2bf(v3); lv.w = f2bf(v3 - bf2f(hv.w));
    const int pix = (b * 20 + oy) * 20 + ox;
    *(ushort4*)(xh + pix * 256 + co0) = hv;
    *(ushort4*)(xl + pix * 256 + co0) = lv;
  }
}

// == conv2 weight prep: pw[co][ci][81] fp32 -> wq[k][cc][co][32] bf16 hi/lo ==
// Fragment-ready: a B-fragment (16 co x 8 ci) is a contiguous 1KB block.
__global__ void wprep(const float* __restrict__ pw, unsigned short* __restrict__ wh,
                      unsigned short* __restrict__ wl)
{
  const int co = blockIdx.x;
  const int t  = threadIdx.x;                 // t = ci
  __shared__ float slab[20736];               // [ci][81] for this co
  for (int i = t; i < 20736; i += 256) slab[i] = pw[co * 20736 + i];
  __syncthreads();
  const int cc = t >> 5, ci5 = t & 31;
  for (int k = 0; k < 81; k++) {
    float x = slab[t * 81 + k];
    unsigned short h = f2bf(x);
    int dst = ((k * 8 + cc) * 256 + co) * 32 + ci5;
    wh[dst] = h;
    wl[dst] = f2bf(x - bf2f(h));
  }
}

// ===== conv2 MFMA: block 64pix x 256co, 4 waves (wave 64x64), kg=3 split ====
// grid 432 = 144 m-tiles x 3 ky-groups; 256 thr; 24KB LDS (A only, 3 bufs).
// A swizzle: granule g=(row*4+ch) at slot s=g^(row&7) (verified involution);
// staging inverts on the per-lane global address, LDS dest linear.
__global__ __launch_bounds__(256) void conv2_mfma(
    const unsigned short* __restrict__ xh, const unsigned short* __restrict__ xl,
    const unsigned short* __restrict__ wh, const unsigned short* __restrict__ wl,
    float* __restrict__ part)
{
  __shared__ char lds[24576];
  const int t   = threadIdx.x;
  const int blk = blockIdx.x;
  const int mt  = blk % 144;
  const int kg  = blk / 144;
  const int m0  = mt * 64;
  const int lane = t & 63;
  const int w    = t >> 6;
  const int l15  = lane & 15, l4 = lane >> 4;

  // staging source decode: slot t holds granule g = inv(t)
  const int ib2 = ((t >> 2) ^ (t >> 4)) & 1;
  const int ib1 = ((t >> 1) ^ (t >> 3)) & 1;
  const int ib0 = (t ^ (t >> 2) ^ (t >> 4)) & 1;
  const int g   = (t & ~7) | (ib2 << 2) | (ib1 << 1) | ib0;
  const int ar  = g >> 2, ach = g & 3;
  const int apix = m0 + ar;
  const int ab  = apix / 36;
  const int asp = apix - ab * 36;
  const int aoy = asp / 6;
  const int aox = asp - aoy * 6;
  const int abase = ((ab * 20 + 2 * aoy) * 20 + 2 * aox) * 256 + ach * 8;

  const int bofs = (w * 64 + l15) * 32 + l4 * 8;   // into one (k,cc) weight slab

  f32x4 acc[4][4];
  #pragma unroll
  for (int i = 0; i < 4; i++)
    #pragma unroll
    for (int j = 0; j < 4; j++) acc[i][j] = (f32x4){0.f, 0.f, 0.f, 0.f};

  const int ky0 = kg * 3;

  auto stageA = [&](int buf, int axy) {
    char* base = lds + buf * 8192;
    gload16(xh + abase + axy, base + t * 16);
    gload16(xl + abase + axy, base + 4096 + t * 16);
  };

  stageA(0, (ky0 * 20) * 256);
  int kyc = ky0, kxc = 0, ccc = 0;               // current step indices
  #pragma unroll 1
  for (int s = 0; s < 216; ++s) {
    // B fragments for CURRENT step: 8 x 16B register loads (L2-resident).
    // Issued BEFORE the next A-stage so the compiler's auto-vmcnt for b uses
    // never has to drain the in-flight DMA (b loads are older).
    const int slab = ((kyc * 9 + kxc) * 8 + ccc) * 8192;
    const unsigned short* bhp = wh + slab + bofs;
    const unsigned short* blp = wl + slab + bofs;
    short8 b_h[4], b_l[4];
    #pragma unroll
    for (int nf = 0; nf < 4; nf++) {
      b_h[nf] = *(const short8*)(bhp + nf * 512);
      b_l[nf] = *(const short8*)(blp + nf * 512);
    }
    // advance indices, prefetch next A chunk
    ccc++;
    if (ccc == 8) { ccc = 0; kxc++; if (kxc == 9) { kxc = 0; kyc++; } }
    if (s < 215) {
      stageA((s + 1) % 3, (kyc * 20 + kxc) * 256 + ccc * 32);
      asm volatile("s_waitcnt vmcnt(10)" ::: "memory");  // A(s) done; A(s+1)+B in flight
    } else {
      asm volatile("s_waitcnt vmcnt(8)" ::: "memory");
    }
    asm volatile("s_barrier" ::: "memory");

    char* base = lds + (s % 3) * 8192;
    short8 a_h[4], a_l[4];
    #pragma unroll
    for (int mf = 0; mf < 4; mf++) {
      const int row = mf * 16 + l15;
      const int off = ((((row << 2) | l4) ^ (l15 & 7)) << 4);
      a_h[mf] = *(const short8*)(base + off);
      a_l[mf] = *(const short8*)(base + 4096 + off);
    }
    __builtin_amdgcn_s_setprio(1);
    #pragma unroll
    for (int nf = 0; nf < 4; nf++)
      #pragma unroll
      for (int mf = 0; mf < 4; mf++) {
        f32x4 a = acc[mf][nf];
        a = __builtin_amdgcn_mfma_f32_16x16x32_bf16(a_h[mf], b_h[nf], a, 0, 0, 0);
        a = __builtin_amdgcn_mfma_f32_16x16x32_bf16(a_l[mf], b_h[nf], a, 0, 0, 0);
        a = __builtin_amdgcn_mfma_f32_16x16x32_bf16(a_h[mf], b_l[nf], a, 0, 0, 0);
        acc[mf][nf] = a;
      }
    __builtin_amdgcn_s_setprio(0);
    // pin ds_read retirement before the next barrier (triple-buffer safety)
    asm volatile("s_waitcnt lgkmcnt(0)" ::: "memory");
  }

  // epilogue: C[pix][co]; 16x16 C/D: col=lane&15, row=(lane>>4)*4+reg
  float* pout = part + kg * 2359296;
  #pragma unroll
  for (int mf = 0; mf < 4; mf++)
    #pragma unroll
    for (int nf = 0; nf < 4; nf++) {
      const int co = w * 64 + nf * 16 + l15;
      #pragma unroll
      for (int reg = 0; reg < 4; reg++) {
        const int pix = m0 + mf * 16 + l4 * 4 + reg;
        const int b  = pix / 36;
        const int sp = pix - b * 36;
        pout[b * 9216 + co * 36 + sp] = acc[mf][nf][reg];
      }
    }
}

// ======== combine 3 split-K partials + bias, squash(8); emit u_T only =======
__global__ void combine_squash(const float* __restrict__ part,
                               const float* __restrict__ pb,
                               float* __restrict__ uT)
{
  const int id = blockIdx.x * 256 + threadIdx.x;  // 0..294911
  const int b = id / 1152;
  const int r = id % 1152;
  const float* p0 = part + b * 9216 + r * 8;
  float v[8];
  #pragma unroll
  for (int i = 0; i < 8; i++) v[i] = p0[i] + p0[2359296 + i] + p0[4718592 + i];
  #pragma unroll
  for (int i = 0; i < 8; i++) v[i] += pb[(r * 8 + i) / 36];
  float sq = 0.f;
  #pragma unroll
  for (int i = 0; i < 8; i++) sq += v[i] * v[i];
  float scale = sq / ((1.f + sq) * sqrtf(sq));
  #pragma unroll
  for (int i = 0; i < 8; i++) uT[(r * 256 + b) * 8 + i] = v[i] * scale;
}

// ===== s partials: grid 640 = 10 c x 64 r-chunks(18); block 256 (thread=b) ==
__global__ __launch_bounds__(256) void s_pass(
    const float* __restrict__ uT, const float* __restrict__ Wdc,
    const float* __restrict__ bij, float* __restrict__ spart, int uniform)
{
  const int c  = blockIdx.x % 10;
  const int q  = blockIdx.x / 10;          // 0..63
  const int r0 = q * 18;
  const int t  = threadIdx.x;
  __shared__ float wsm[18 * 128];          // 9216 B
  __shared__ float cw[18];
  __shared__ float red[8];

  #pragma unroll
  for (int k = 0; k < 9; k++) {
    int idx = t + k * 256;                 // < 2304
    int r = idx >> 7, i = idx & 127;
    wsm[idx] = Wdc[((r0 + r) * 10 + c) * 128 + i];
  }
  if (uniform) {
    if (t < 18) cw[t] = 1.f / 1152.f;
  } else {
    float bv[5]; float m = -1e30f;
    #pragma unroll
    for (int rr = 0; rr < 5; rr++) {
      int r = t + rr * 256;
      bv[rr] = (r < 1152) ? bij[c * 1152 + r] : -1e30f;
      m = fmaxf(m, bv[rr]);
    }
    #pragma unroll
    for (int off = 32; off; off >>= 1) m = fmaxf(m, __shfl_down(m, off, 64));
    if ((t & 63) == 0) red[t >> 6] = m;
    __syncthreads();
    m = fmaxf(fmaxf(red[0], red[1]), fmaxf(red[2], red[3]));
    float ssum = 0.f;
    #pragma unroll
    for (int rr = 0; rr < 5; rr++)
      ssum += (t + rr * 256 < 1152) ? expf(bv[rr] - m) : 0.f;
    #pragma unroll
    for (int off = 32; off; off >>= 1) ssum += __shfl_down(ssum, off, 64);
    if ((t & 63) == 0) red[4 + (t >> 6)] = ssum;
    __syncthreads();
    float inv = 1.f / (red[4] + red[5] + red[6] + red[7]);
    if (t < 18) cw[t] = expf(bij[c * 1152 + r0 + t] - m) * inv;
  }
  __syncthreads();

  const float4* up = (const float4*)(uT + (r0 * 256 + t) * 8);
  float acc[16];
  #pragma unroll
  for (int o = 0; o < 16; o++) acc[o] = 0.f;
  #pragma unroll 1
  for (int r = 0; r < 18; r++) {
    float4 x0 = up[r * 512], x1 = up[r * 512 + 1];
    float cwr = cw[r];
    const float* wr = &wsm[r * 128];
    #pragma unroll
    for (int o = 0; o < 16; o++) {
      const float4 wa = *(const float4*)(wr + o * 8);
      const float4 wb = *(const float4*)(wr + o * 8 + 4);
      acc[o] += cwr * (wa.x*x0.x + wa.y*x0.y + wa.z*x0.z + wa.w*x0.w
                     + wb.x*x1.x + wb.y*x1.y + wb.z*x1.z + wb.w*x1.w);
    }
  }
  float* op = spart + q * 40960 + (t * 10 + c) * 16;
  #pragma unroll
  for (int o = 0; o < 16; o++) op[o] = acc[o];
}

// ===== fused: sum 64 r-chunk partials; non-final: squash -> vT; final: sbuf =
template <int FINAL>
__global__ void reduce_squash(const float* __restrict__ spart, float* __restrict__ outb)
{
  const int id = blockIdx.x * 256 + threadIdx.x;   // < 40960; id=(b*10+c)*16+o
  float a = 0.f;
  #pragma unroll 8
  for (int q = 0; q < 64; q++) a += spart[q * 40960 + id];
  if (FINAL) { outb[id] = a; return; }
  float sq = a * a;
  #pragma unroll
  for (int off = 8; off; off >>= 1) sq += __shfl_xor(sq, off, 16);
  float scale = sq / ((1.f + sq) * sqrtf(sq));
  const int bc = id >> 4, o = id & 15;
  const int b = bc / 10, c = bc - b * 10;
  outb[(c * 256 + b) * 16 + o] = a * scale;
}

// == a[r,c] = (1/B) sum_{b,o} dot(W[r,c,o],u[b,r]) * v[b,c,o]; bij (+)= a ====
__global__ __launch_bounds__(256) void a_pass(
    const float* __restrict__ uT, const float* __restrict__ W,
    const float* __restrict__ vT, float* __restrict__ bij, int assign)
{
  const int r = blockIdx.x;
  const int t = threadIdx.x;
  __shared__ float wsl[1280];
  __shared__ float lred[4][10];
  for (int i = t; i < 1280; i += 256) wsl[i] = W[r * 1280 + i];
  __syncthreads();
  const float4* up = (const float4*)(uT + (r * 256 + t) * 8);
  float4 ua = up[0], ub = up[1];
  const int lane = t & 63, wid = t >> 6;
  #pragma unroll 1
  for (int c = 0; c < 10; c++) {
    const float* wc = &wsl[c * 128];
    const float4* vp = (const float4*)(vT + (c * 256 + t) * 16);
    float p = 0.f;
    #pragma unroll
    for (int q = 0; q < 4; q++) {
      float4 vq = vp[q];
      p += dot8(wc + (q * 4 + 0) * 8, ua, ub) * vq.x;
      p += dot8(wc + (q * 4 + 1) * 8, ua, ub) * vq.y;
      p += dot8(wc + (q * 4 + 2) * 8, ua, ub) * vq.z;
      p += dot8(wc + (q * 4 + 3) * 8, ua, ub) * vq.w;
    }
    for (int off = 32; off; off >>= 1) p += __shfl_down(p, off, 64);
    if (lane == 0) lred[wid][c] = p;
  }
  __syncthreads();
  if (t < 10) {
    float a = (lred[0][t] + lred[1][t] + lred[2][t] + lred[3][t]) * (1.f / 256.f);
    float o = assign ? 0.f : bij[t * 1152 + r];
    bij[t * 1152 + r] = o + a;
  }
}

// == finalize: squash(final) -> outp; batch softmax; argmax mask; t vector ===
__global__ __launch_bounds__(256) void finalize(
    const float* __restrict__ sbuf, float* __restrict__ outp,
    float* __restrict__ maskedo, float* __restrict__ tbuf)
{
  const int b = threadIdx.x;
  __shared__ float nsm[256][10];
  __shared__ float red[8];
  #pragma unroll 1
  for (int c = 0; c < 10; c++) {
    const float4* sp = (const float4*)(sbuf + (b * 10 + c) * 16);
    float4 q0 = sp[0], q1 = sp[1], q2 = sp[2], q3 = sp[3];
    float sq = q0.x*q0.x+q0.y*q0.y+q0.z*q0.z+q0.w*q0.w
             + q1.x*q1.x+q1.y*q1.y+q1.z*q1.z+q1.w*q1.w
             + q2.x*q2.x+q2.y*q2.y+q2.z*q2.z+q2.w*q2.w
             + q3.x*q3.x+q3.y*q3.y+q3.z*q3.z+q3.w*q3.w;
    float scale = sq / ((1.f + sq) * sqrtf(sq));
    float4* op = (float4*)(outp + (b * 10 + c) * 16);
    op[0] = make_float4(q0.x*scale, q0.y*scale, q0.z*scale, q0.w*scale);
    op[1] = make_float4(q1.x*scale, q1.y*scale, q1.z*scale, q1.w*scale);
    op[2] = make_float4(q2.x*scale, q2.y*scale, q2.z*scale, q2.w*scale);
    op[3] = make_float4(q3.x*scale, q3.y*scale, q3.z*scale, q3.w*scale);
    nsm[b][c] = sq / (1.f + sq);          // = ||squash(s)||
  }
  __syncthreads();
  float sc[10];
  #pragma unroll
  for (int c = 0; c < 10; c++) {
    float x = nsm[b][c];
    float m = x;
    #pragma unroll
    for (int off = 32; off; off >>= 1) m = fmaxf(m, __shfl_down(m, off, 64));
    if ((b & 63) == 0) red[b >> 6] = m;
    __syncthreads();
    m = fmaxf(fmaxf(red[0], red[1]), fmaxf(red[2], red[3]));
    float e = expf(x - m), ss = e;
    #pragma unroll
    for (int off = 32; off; off >>= 1) ss += __shfl_down(ss, off, 64);
    if ((b & 63) == 0) red[4 + (b >> 6)] = ss;
    __syncthreads();
    sc[c] = e / (red[4] + red[5] + red[6] + red[7]);
    __syncthreads();
  }
  int idx = 0; float best = sc[0];
  #pragma unroll
  for (int c = 1; c < 10; c++) if (sc[c] > best) { best = sc[c]; idx = c; }
  #pragma unroll
  for (int c = 0; c < 10; c++) {
    float msk = (c == idx) ? 1.f : 0.f;
    maskedo[b * 10 + c] = msk;
    const float4* op = (const float4*)(outp + (b * 10 + c) * 16);
    float4* tp = (float4*)(tbuf + b * 160 + c * 16);
    #pragma unroll
    for (int qq = 0; qq < 4; qq++) {
      float4 vv = op[qq];
      tp[qq] = make_float4(vv.x * msk, vv.y * msk, vv.z * msk, vv.w * msk);
    }
  }
}

// ==================== small GEMM: C = act(A[M,K] @ B[K,N] + bias) ===========
template <int ACT>
__global__ __launch_bounds__(256) void gemm_act(
    const float* __restrict__ A, const float* __restrict__ B,
    const float* __restrict__ bias, float* __restrict__ C, int M, int N, int K)
{
  __shared__ float As[64][17];
  __shared__ float Bs[16][64];
  const int t = threadIdx.x;
  const int tx = t & 15, ty = t >> 4;
  const int m0 = blockIdx.y * 64, n0 = blockIdx.x * 64;
  float acc[4][4] = {};
  for (int kb = 0; kb < K; kb += 16) {
    {
      int row = t >> 2, c4 = (t & 3) * 4;
      float4 av = *(const float4*)(A + (m0 + row) * K + kb + c4);
      As[row][c4+0]=av.x; As[row][c4+1]=av.y; As[row][c4+2]=av.z; As[row][c4+3]=av.w;
    }
    {
      int row = t >> 4, c4 = (t & 15) * 4;
      float4 bv = make_float4(0.f, 0.f, 0.f, 0.f);
      if (n0 + c4 < N) bv = *(const float4*)(B + (kb + row) * N + n0 + c4);
      Bs[row][c4+0]=bv.x; Bs[row][c4+1]=bv.y; Bs[row][c4+2]=bv.z; Bs[row][c4+3]=bv.w;
    }
    __syncthreads();
    #pragma unroll
    for (int kk = 0; kk < 16; kk++) {
      float a_[4], b_[4];
      #pragma unroll
      for (int i = 0; i < 4; i++) a_[i] = As[ty * 4 + i][kk];
      #pragma unroll
      for (int j = 0; j < 4; j++) b_[j] = Bs[kk][tx * 4 + j];
      #pragma unroll
      for (int i = 0; i < 4; i++)
        for (int j = 0; j < 4; j++)
          acc[i][j] = fmaf(a_[i], b_[j], acc[i][j]);
    }
    __syncthreads();
  }
  #pragma unroll
  for (int i = 0; i < 4; i++) {
    int row = m0 + ty * 4 + i;
    #pragma unroll
    for (int j = 0; j < 4; j++) {
      int col = n0 + tx * 4 + j;
      if (col < N) {
        float val = acc[i][j] + bias[col];
        if (ACT == 0) val = val > 0.f ? val : 0.f;
        else          val = 1.f / (1.f + expf(-val));
        C[row * N + col] = val;
      }
    }
  }
}

// ===========================================================================
extern "C" void kernel_launch(void* const* d_in, const int* in_sizes, int n_in,
                              void* d_out, int out_size, void* d_ws, size_t ws_size,
                              hipStream_t stream)
{
  const float* data = (const float*)d_in[0];
  const float* w1   = (const float*)d_in[1];
  const float* b1   = (const float*)d_in[2];
  const float* pw   = (const float*)d_in[3];
  const float* pb   = (const float*)d_in[4];
  const float* Wdc  = (const float*)d_in[5];
  const float* dw1  = (const float*)d_in[6];
  const float* db1  = (const float*)d_in[7];
  const float* dw2  = (const float*)d_in[8];
  const float* db2  = (const float*)d_in[9];
  const float* dw3  = (const float*)d_in[10];
  const float* db3  = (const float*)d_in[11];

  float* out     = (float*)d_out;
  float* outp    = out;              // [256][10][16][1]
  float* recon   = out + 40960;      // [256][784]
  float* maskedo = out + 241664;     // [256][10]

  char* wsb = (char*)d_ws;
  // big section (conv phase)
  unsigned short* x1h = (unsigned short*)(wsb);               // 52,428,800 B
  unsigned short* x1l = (unsigned short*)(wsb + 52428800);    // 52,428,800
  unsigned short* wbh = (unsigned short*)(wsb + 104857600);   // 10,616,832
  unsigned short* wbl = (unsigned short*)(wsb + 115474432);   // 10,616,832
  float*  part = (float*)(wsb + 126091264);                   // 28,311,552
  // overlay section (x1h region is dead after conv2)
  float* uT   = (float*)(wsb);                                //  9,437,184
  float* vT   = (float*)(wsb + 9437184);                      //    163,840
  float* bij  = (float*)(wsb + 9601024);                      //     46,080
  float* sbuf = (float*)(wsb + 9647104);                      //    163,840
  float* spart= (float*)(wsb + 9810944);                      // 10,485,760
  float* tbuf = (float*)(wsb + 20296704);                     //    163,840
  float* h1   = (float*)(wsb + 20460544);                     //    524,288
  float* h2   = (float*)(wsb + 20984832);                     //  1,048,576

  conv1_kernel<<<1024, 320, 0, stream>>>(data, w1, b1, x1h, x1l);
  wprep<<<256, 256, 0, stream>>>(pw, wbh, wbl);
  conv2_mfma<<<432, 256, 0, stream>>>(x1h, x1l, wbh, wbl, part);
  combine_squash<<<1152, 256, 0, stream>>>(part, pb, uT);

  // routing iteration 0 (b_ij = 0 -> uniform c); b_ij assigned, not added
  s_pass<<<640, 256, 0, stream>>>(uT, Wdc, bij, spart, 1);
  reduce_squash<0><<<160, 256, 0, stream>>>(spart, vT);
  a_pass<<<1152, 256, 0, stream>>>(uT, Wdc, vT, bij, 1);
  // iteration 1
  s_pass<<<640, 256, 0, stream>>>(uT, Wdc, bij, spart, 0);
  reduce_squash<0><<<160, 256, 0, stream>>>(spart, vT);
  a_pass<<<1152, 256, 0, stream>>>(uT, Wdc, vT, bij, 0);
  // iteration 2 (final) + fused decoder head
  s_pass<<<640, 256, 0, stream>>>(uT, Wdc, bij, spart, 0);
  reduce_squash<1><<<160, 256, 0, stream>>>(spart, sbuf);
  finalize<<<1, 256, 0, stream>>>(sbuf, outp, maskedo, tbuf);

  gemm_act<0><<<dim3(8, 4),  256, 0, stream>>>(tbuf, dw1, db1, h1,    256, 512,  160);
  gemm_act<0><<<dim3(16, 4), 256, 0, stream>>>(h1,   dw2, db2, h2,    256, 1024, 512);
  gemm_act<1><<<dim3(13, 4), 256, 0, stream>>>(h2,   dw3, db3, recon, 256, 784,  1024);
}